// Round 13
// baseline (699.877 us; speedup 1.0000x reference)
//
#include <hip/hip_runtime.h>
#include <hip/hip_bf16.h>
#include <math.h>

#define CHUNK 16
#define NN 1764
#define SORTN 2048

typedef float v2f __attribute__((ext_vector_type(2)));

// async global->LDS, 16B per lane. LDS arg must be wave-uniform base; HW adds lane*16.
__device__ inline void gl_lds16(const float* g, float* l) {
  __builtin_amdgcn_global_load_lds(
      (const __attribute__((address_space(1))) void*)g,
      (__attribute__((address_space(3))) void*)l, 16, 0, 0);
}

// ---------------- weight packing ----------------
// Direct-conv packing (conv2/conv3): W[co][ci][3][3] -> Wpk[ci][p][20],
// pair p=(co>>5)*16+(co&15), h=(co&31)>>4 -> slot 2*k+h.
template<int Co, int Ci>
__device__ inline void seg_pack_pk(const float* __restrict__ src, float* __restrict__ dst, int i) {
  int co = i / (Ci * 9); int rem = i - co * (Ci * 9); int ci = rem / 9; int k = rem - ci * 9;
  int p = (co >> 5) * 16 + (co & 15);
  int h = (co & 31) >> 4;
  dst[((size_t)ci * (Co >> 1) + p) * 20 + 2 * k + h] = src[i];
}
template<int Co, int CiK>
__device__ inline void seg_tr(const float* __restrict__ src, float* __restrict__ dst, int i) {
  int co = i / CiK; int cik = i - co * CiK;
  dst[cik * Co + co] = src[i];
}

// R17/R22: Winograd F(2,3) weight transform for conv1.
// U = G g G^T (exact fp32). R22 layout: the 4 u2 fragments for one col are 8
// CONSECUTIVE floats (2x ds_read_b128, 2-way bank alias = free); LDS staging
// stays a LINEAR copy (global_load_lds compatible).
__device__ inline void seg_wino_u(const float* __restrict__ src, float* __restrict__ dst, int i) {
  int ci = i >> 8;            // i = ci*256 + co
  int co = i & 255;
  const float* g = src + ((size_t)co * 512 + ci) * 9;
  float g00=g[0],g01=g[1],g02=g[2],g10=g[3],g11=g[4],g12=g[5],g20=g[6],g21=g[7],g22=g[8];
  float a[4][3];
  a[0][0]=g00; a[0][1]=g01; a[0][2]=g02;
  a[1][0]=0.5f*(g00+g10+g20); a[1][1]=0.5f*(g01+g11+g21); a[1][2]=0.5f*(g02+g12+g22);
  a[2][0]=0.5f*(g00-g10+g20); a[2][1]=0.5f*(g01-g11+g21); a[2][2]=0.5f*(g02-g12+g22);
  a[3][0]=g20; a[3][1]=g21; a[3][2]=g22;
  const int p_old = (co >> 5) * 16 + (co & 15);
  const int h = (co & 31) >> 4;
  const int pb = p_old >> 6, loc = p_old & 63;
  const int gg = loc >> 4, col = loc & 15;
  const int P = pb * 64 + (gg >> 1) * 32 + col * 2 + (gg & 1);
#pragma unroll
  for (int r4 = 0; r4 < 4; ++r4) {
    float u0 = a[r4][0];
    float u1 = 0.5f * (a[r4][0] + a[r4][1] + a[r4][2]);
    float u2 = 0.5f * (a[r4][0] - a[r4][1] + a[r4][2]);
    float u3 = a[r4][2];
    float uv[4] = {u0, u1, u2, u3};
#pragma unroll
    for (int c4 = 0; c4 < 4; ++c4) {
      int pos = r4 * 4 + c4;
      dst[(((size_t)pos * 512 + ci) * 128 + P) * 2 + h] = uv[c4];
    }
  }
}

__global__ void wtrans_all(
  const float* __restrict__ b1w, const float* __restrict__ c1w,
  const float* __restrict__ b2w, const float* __restrict__ c2w,
  const float* __restrict__ b3w, const float* __restrict__ b4w,
  const float* __restrict__ c3w,
  float* __restrict__ ub, float* __restrict__ uc,
  float* __restrict__ wp2b, float* __restrict__ wp2c,
  float* __restrict__ wp3b, float* __restrict__ wt4b, float* __restrict__ wt3c)
{
  int j = blockIdx.x * blockDim.x + threadIdx.x;
  if (j < 131072) { seg_wino_u(b1w, ub, j); return; } j -= 131072;
  if (j < 131072) { seg_wino_u(c1w, uc, j); return; } j -= 131072;
  if (j < 294912) { seg_pack_pk<128, 256>(b2w, wp2b, j); return; } j -= 294912;
  if (j < 294912) { seg_pack_pk<128, 256>(c2w, wp2c, j); return; } j -= 294912;
  if (j < 147456) { seg_pack_pk<128, 128>(b3w, wp3b, j); return; } j -= 147456;
  if (j < 4608)   { seg_tr<36, 128>(b4w, wt4b, j); return; }  j -= 4608;
  if (j < 1152)   { seg_tr<9, 128>(c3w, wt3c, j); return; }
}

// ---------------- R17: Winograd input transform (conv1) ----------------
__global__ __launch_bounds__(256) void wino_in(
    const float* __restrict__ f, float* __restrict__ V)
{
  const int b = blockIdx.x, cig = blockIdx.y, tid = threadIdx.x;
  if (tid >= 196) return;
  const int ci = cig * 4 + tid / 49;
  const int t  = tid % 49;
  const int ty = t / 7, tx = t % 7;
  const float* fp = f + ((size_t)b * 512 + ci) * 196;
  const int y0 = 2 * ty - 1, x0 = 2 * tx - 1;
  float d[4][4];
#pragma unroll
  for (int i = 0; i < 4; ++i) {
    const int y = y0 + i;
#pragma unroll
    for (int j = 0; j < 4; ++j) {
      const int x = x0 + j;
      d[i][j] = (y >= 0 && y < 14 && x >= 0 && x < 14) ? fp[y * 14 + x] : 0.0f;
    }
  }
  float tr[4][4];
#pragma unroll
  for (int j = 0; j < 4; ++j) {
    tr[0][j] = d[0][j] - d[2][j];
    tr[1][j] = d[1][j] + d[2][j];
    tr[2][j] = d[2][j] - d[1][j];
    tr[3][j] = d[1][j] - d[3][j];
  }
  const size_t m = (size_t)b * 49 + t;
#pragma unroll
  for (int i = 0; i < 4; ++i) {
    float v0 = tr[i][0] - tr[i][2];
    float v1 = tr[i][1] + tr[i][2];
    float v2 = tr[i][2] - tr[i][1];
    float v3 = tr[i][1] - tr[i][3];
    V[((size_t)(i * 4 + 0) * 512 + ci) * 1568 + m] = v0;
    V[((size_t)(i * 4 + 1) * 512 + ci) * 1568 + m] = v1;
    V[((size_t)(i * 4 + 2) * 512 + ci) * 1568 + m] = v2;
    V[((size_t)(i * 4 + 3) * 512 + ci) * 1568 + m] = v3;
  }
}

// ---------------- R23: Winograd GEMM (R22 body, 3 waves/EU) ----------------
// R22: gl_lds staging + b128 u-reads: 216us, VALUBusy 50, bank-conflicts 0,
//   WRITE=50MB (no spill). Remaining limit: per-ci ds_read->FMA chain (~2.9k
//   cyc serial/phase vs 1.1k issue); 2 waves only half-cover it.
// R23: retry (256,3). R20's spill at cap 84 was with 12 reg-staged prefetch
//   regs + ds_write addressing; gl_lds removed those -> demand ~70-80 should
//   now FIT under 84. Tripwire: WRITE must stay 50MB, else revert for good.
__global__ __launch_bounds__(256, 3) void wino_gemm(
    const float* __restrict__ V, const float* __restrict__ U, float* __restrict__ M)
{
  const int pos = blockIdx.x;     // 0..15
  const int mb  = blockIdx.y;     // 0..24
  const int q   = blockIdx.z;     // 0..3
  const int head = q >> 1;
  const int pb   = q & 1;
  const int tid = threadIdx.x;
  const int col = tid & 15;
  const int r   = tid >> 4;
  const int wv  = tid >> 6;       // wave id (LDS base must be wave-uniform)

  __shared__ float vbuf[2][16][64];    // 8 KB  (linear: buf*1024 + tid*4 floats)
  __shared__ float ubuf[2][16][128];   // 16 KB (linear: buf*2048 + k*1024 + tid*4)

  const float* Uh = U + (size_t)head * 2097152;
  float* Mh = M + (size_t)head * 6422528;
  const int m0 = mb * 64;

  // per-lane global sources (lane tid writes LDS float offset tid*4)
  const float* vg  = V + ((size_t)pos * 512 + (tid >> 4)) * 1568 + m0 + (tid & 15) * 4;
  const int c1 = 256 + tid;
  const float* ug0 = Uh + ((size_t)pos * 512 + (tid >> 5)) * 256 + pb * 128 + (tid & 31) * 4;
  const float* ug1 = Uh + ((size_t)pos * 512 + (c1 >> 5)) * 256 + pb * 128 + (c1 & 31) * 4;
  // wave-uniform LDS bases
  float* vls = ((float*)vbuf) + wv * 256;
  float* uls = ((float*)ubuf) + wv * 256;

  // prologue: stage cb=0 into buffer 0
  gl_lds16(vg, vls);
  gl_lds16(ug0, uls);
  gl_lds16(ug1, uls + 1024);
  __syncthreads();   // implicit vmcnt(0) drain

  v2f acc[4][4];
#pragma unroll
  for (int g = 0; g < 4; ++g)
#pragma unroll
    for (int j = 0; j < 4; ++j) acc[g][j] = (v2f)(0.0f);

  int cur = 0;
  for (int cb = 0; cb < 32; ++cb) {
    // issue next phase's async loads; they fly during this phase's compute
    if (cb + 1 < 32) {
      const int nb = cur ^ 1;
      gl_lds16(vg + (size_t)(cb + 1) * 16 * 1568, vls + nb * 1024);
      gl_lds16(ug0 + (size_t)(cb + 1) * 16 * 256, uls + nb * 2048);
      gl_lds16(ug1 + (size_t)(cb + 1) * 16 * 256, uls + nb * 2048 + 1024);
    }
#pragma unroll
    for (int ci = 0; ci < 16; ++ci) {
      const float4* uq0 = (const float4*)&ubuf[cur][ci][col * 4];        // g0,g1
      const float4* uq1 = (const float4*)&ubuf[cur][ci][64 + col * 4];   // g2,g3
      float4 a = uq0[0], bq = uq1[0];
      v2f u2[4] = { (v2f){a.x, a.y}, (v2f){a.z, a.w},
                    (v2f){bq.x, bq.y}, (v2f){bq.z, bq.w} };
      const float4* vp = (const float4*)&vbuf[cur][ci][r * 4];
      float4 v0 = vp[0];
      float vv[4] = {v0.x, v0.y, v0.z, v0.w};
#pragma unroll
      for (int j = 0; j < 4; ++j) {
        v2f s2 = (v2f){vv[j], vv[j]};
#pragma unroll
        for (int g = 0; g < 4; ++g)
          acc[g][j] = __builtin_elementwise_fma(u2[g], s2, acc[g][j]);
      }
    }
    __syncthreads();   // drains vmcnt (next-buffer loads) + all reads done
    cur ^= 1;
  }

  const int mm = m0 + r * 4;
  if (mm < 1568) {
#pragma unroll
    for (int g = 0; g < 4; ++g) {
      const int p = pb * 64 + g * 16 + col;
      const int cox = (p >> 4) * 32 + (p & 15);
      float* ox = Mh + ((size_t)pos * 256 + cox) * 1568 + mm;
      float* oy = ox + (size_t)16 * 1568;
#pragma unroll
      for (int j = 0; j < 4; ++j) { ox[j] = acc[g][j].x; oy[j] = acc[g][j].y; }
    }
  }
}

// ---------------- R17: Winograd output transform + bias + GELU + GN (conv1) ----------------
__global__ __launch_bounds__(256) void wino_out_gn(
    const float* __restrict__ M,
    const float* __restrict__ bsb, const float* __restrict__ bsc,
    const float* __restrict__ gwb, const float* __restrict__ gwc,
    const float* __restrict__ gbb, const float* __restrict__ gbc,
    float* __restrict__ outb, float* __restrict__ outc)
{
  const int bx = blockIdx.x;           // 0..31: head = bx>>4, cog = bx&15
  const int b  = blockIdx.y;
  const int head = bx >> 4, cog = bx & 15;
  const int tid = threadIdx.x;
  const float* Mh = M + (size_t)head * 6422528;
  const float* bs = head ? bsc : bsb;
  const float* gw = head ? gwc : gwb;
  const float* gb = head ? gbc : gbb;
  float* out      = head ? outc : outb;
  const int co0 = cog * 16;

  __shared__ float red[4][4];
  __shared__ float stats[4];

  const bool pa = tid < 196;
  const int csub = tid / 49;
  const int t    = tid % 49;
  const int ty = t / 7, tx = t % 7;
  const size_t mt = (size_t)b * 49 + t;

  float y4[4][4];
  float s = 0.f, q = 0.f;
  if (pa) {
#pragma unroll
    for (int cc = 0; cc < 4; ++cc) {
      const int co = co0 + csub * 4 + cc;
      const float* mp = Mh + (size_t)co * 1568 + mt;
      float m16[16];
#pragma unroll
      for (int pos = 0; pos < 16; ++pos)
        m16[pos] = mp[(size_t)pos * 401408];
      float Z0[4], Z1[4];
#pragma unroll
      for (int j = 0; j < 4; ++j) {
        Z0[j] = m16[0 * 4 + j] + m16[1 * 4 + j] + m16[2 * 4 + j];
        Z1[j] = m16[1 * 4 + j] - m16[2 * 4 + j] - m16[3 * 4 + j];
      }
      const float bias = bs[co];
      float yv[4];
      yv[0] = Z0[0] + Z0[1] + Z0[2];
      yv[1] = Z0[1] - Z0[2] - Z0[3];
      yv[2] = Z1[0] + Z1[1] + Z1[2];
      yv[3] = Z1[1] - Z1[2] - Z1[3];
#pragma unroll
      for (int k = 0; k < 4; ++k) {
        float x = yv[k] + bias;
        float g = 0.5f * x * (1.0f + erff(x * 0.70710678118654752440f));
        y4[cc][k] = g;
        s += g; q += g * g;
      }
    }
  }
  float s0 = (pa && csub < 2) ? s : 0.f, q0 = (pa && csub < 2) ? q : 0.f;
  float s1 = (pa && csub >= 2) ? s : 0.f, q1 = (pa && csub >= 2) ? q : 0.f;
#pragma unroll
  for (int off = 32; off > 0; off >>= 1) {
    s0 += __shfl_down(s0, off, 64); q0 += __shfl_down(q0, off, 64);
    s1 += __shfl_down(s1, off, 64); q1 += __shfl_down(q1, off, 64);
  }
  const int wave = tid >> 6, lane = tid & 63;
  if (lane == 0) { red[wave][0] = s0; red[wave][1] = q0; red[wave][2] = s1; red[wave][3] = q1; }
  __syncthreads();
  if (tid == 0) {
    float S0 = red[0][0] + red[1][0] + red[2][0] + red[3][0];
    float Q0 = red[0][1] + red[1][1] + red[2][1] + red[3][1];
    float S1 = red[0][2] + red[1][2] + red[2][2] + red[3][2];
    float Q1 = red[0][3] + red[1][3] + red[2][3] + red[3][3];
    float m0 = S0 * (1.0f / 1568.0f);
    float v0 = Q0 * (1.0f / 1568.0f) - m0 * m0;
    float m1 = S1 * (1.0f / 1568.0f);
    float v1 = Q1 * (1.0f / 1568.0f) - m1 * m1;
    stats[0] = m0; stats[1] = 1.0f / sqrtf(v0 + 1e-5f);
    stats[2] = m1; stats[3] = 1.0f / sqrtf(v1 + 1e-5f);
  }
  __syncthreads();
  if (pa) {
    const float mg = (csub < 2) ? stats[0] : stats[2];
    const float iv = (csub < 2) ? stats[1] : stats[3];
#pragma unroll
    for (int cc = 0; cc < 4; ++cc) {
      const int co = co0 + csub * 4 + cc;
      const float w = gw[co], bb2 = gb[co];
      float* op = out + ((size_t)b * 256 + co) * 196;
#pragma unroll
      for (int dy = 0; dy < 2; ++dy)
#pragma unroll
        for (int dx = 0; dx < 2; ++dx) {
          float yv = (y4[cc][dy * 2 + dx] - mg) * iv * w + bb2;
          op[(2 * ty + dy) * 14 + (2 * tx + dx)] = yv;
        }
    }
  }
}

// ---------------- split-K partial conv3x3 (conv2/conv3 direct path) ----------------
// NOTE (R10): MFMA/bf16 conv precision-blocked; keep fp32.
// NOTE (R11-R16): ILP/occupancy/setprio all null; LDS-staged weights (R14) and
//   1-barrier dbuf (R15) are load-bearing. Structure ceiling ~59% fp32 ALU.
template<int COPT>
__global__ __launch_bounds__(256, 2) void conv3x3_part(
    const float* __restrict__ in0, const float* __restrict__ in1,
    const float* __restrict__ wt0, const float* __restrict__ wt1,
    float* __restrict__ po0, float* __restrict__ po1,
    int Cin, int Cout, int cobPerHead, int cinPerSplit, size_t sStride)
{
  constexpr int NP = COPT / 2;
  constexpr int NPP = 16 * NP;
  constexpr int NPAIR = 8 * NPP;
  const int tid = threadIdx.x;
  const int bx  = blockIdx.x;
  const int b   = blockIdx.y;
  const int s   = blockIdx.z;
  const int head = bx / cobPerHead;
  const int cob  = bx - head * cobPerHead;
  const float* in  = head ? in1  : in0;
  const float* wt  = head ? wt1  : wt0;
  float* po        = head ? po1  : po0;
  const int co0 = cob * (16 * COPT);

  const int col = tid & 15;
  const int r   = tid >> 4;
  const bool ract = r < 14;

  __shared__ float tile[2][CHUNK][16][16];
  __shared__ float wbuf[2][8][NPP][20];

  {
    float* tz = &tile[0][0][0][0];
    for (int i = tid; i < 2 * CHUNK * 256; i += 256) tz[i] = 0.0f;
  }
  __syncthreads();

  const int p = tid;
  const bool pa = p < 196;
  const int prow = p / 14, pcol = p - prow * 14;
  const float* inb = in + (size_t)b * Cin * 196;
  const int cb0 = (s * cinPerSplit) / CHUNK;
  const int nch = cinPerSplit / CHUNK;
  const int CoutH = Cout >> 1;

  const int sciL = tid / NPP;
  const int spp  = tid - sciL * NPP;
  const bool sact = tid < NPAIR;
  const int spidx = ((co0 >> 5) + (spp >> 4)) * 16 + (spp & 15);

  if (pa) {
#pragma unroll
    for (int ci = 0; ci < CHUNK; ++ci)
      tile[0][ci][prow + 1][pcol + 1] = inb[(cb0 * CHUNK + ci) * 196 + p];
  }
  if (sact) {
    const float4* src = (const float4*)(wt + ((size_t)(cb0 * CHUNK + sciL) * CoutH + spidx) * 20);
    float4 q0 = src[0], q1 = src[1], q2 = src[2], q3 = src[3], q4 = src[4];
    float4* dst = (float4*)&wbuf[0][sciL][spp][0];
    dst[0] = q0; dst[1] = q1; dst[2] = q2; dst[3] = q3; dst[4] = q4;
  }
  __syncthreads();

  v2f acc[NP][14];
#pragma unroll
  for (int g = 0; g < NP; ++g)
#pragma unroll
    for (int j = 0; j < 14; ++j) acc[g][j] = (v2f)(0.0f);

  int wcur = 0;
  for (int lcb = 0; lcb < nch; ++lcb) {
    const int cbg = cb0 + lcb;
    const int cur = lcb & 1;
    const bool more = (lcb + 1 < nch);
    float v[CHUNK];
    if (more && pa) {
#pragma unroll
      for (int ci = 0; ci < CHUNK; ++ci)
        v[ci] = inb[((cbg + 1) * CHUNK + ci) * 196 + p];
    }
#pragma unroll
    for (int half = 0; half < 2; ++half) {
      const bool hasNext = (half == 0) || more;
      const int nbase = (half == 0) ? (cbg * CHUNK + 8) : ((cbg + 1) * CHUNK);
      float4 q0, q1, q2, q3, q4;
      if (hasNext && sact) {
        const float4* src = (const float4*)(wt + ((size_t)(nbase + sciL) * CoutH + spidx) * 20);
        q0 = src[0]; q1 = src[1]; q2 = src[2]; q3 = src[3]; q4 = src[4];
      }
      if (ract) {
#pragma unroll
        for (int ciL = 0; ciL < 8; ++ciL) {
          const int ci = half * 8 + ciL;
          v2f w2[NP][9];
#pragma unroll
          for (int g = 0; g < NP; ++g) {
            const float4* wq = (const float4*)&wbuf[wcur][ciL][g * 16 + col][0];
            float4 a0 = wq[0], a1 = wq[1], a2 = wq[2], a3 = wq[3], a4 = wq[4];
            w2[g][0] = (v2f){a0.x, a0.y}; w2[g][1] = (v2f){a0.z, a0.w};
            w2[g][2] = (v2f){a1.x, a1.y}; w2[g][3] = (v2f){a1.z, a1.w};
            w2[g][4] = (v2f){a2.x, a2.y}; w2[g][5] = (v2f){a2.z, a2.w};
            w2[g][6] = (v2f){a3.x, a3.y}; w2[g][7] = (v2f){a3.z, a3.w};
            w2[g][8] = (v2f){a4.x, a4.y};
          }
          float nb[3][16];
#pragma unroll
          for (int dr = 0; dr < 3; ++dr) {
            const float4* rp = (const float4*)(&tile[cur][ci][r + dr][0]);
            float4 a = rp[0], bq = rp[1], cq = rp[2], dq = rp[3];
            nb[dr][0]  = a.x;  nb[dr][1]  = a.y;  nb[dr][2]  = a.z;  nb[dr][3]  = a.w;
            nb[dr][4]  = bq.x; nb[dr][5]  = bq.y; nb[dr][6]  = bq.z; nb[dr][7]  = bq.w;
            nb[dr][8]  = cq.x; nb[dr][9]  = cq.y; nb[dr][10] = cq.z; nb[dr][11] = cq.w;
            nb[dr][12] = dq.x; nb[dr][13] = dq.y; nb[dr][14] = dq.z; nb[dr][15] = dq.w;
          }
#pragma unroll
          for (int ky = 0; ky < 3; ++ky)
#pragma unroll
            for (int kx = 0; kx < 3; ++kx) {
#pragma unroll
              for (int g = 0; g < NP; ++g) {
                v2f w = w2[g][ky * 3 + kx];
#pragma unroll
                for (int j = 0; j < 14; ++j) {
                  float s_ = nb[ky][j + kx];
                  v2f nbv = (v2f){s_, s_};
                  acc[g][j] = __builtin_elementwise_fma(w, nbv, acc[g][j]);
                }
              }
            }
        }
      }
      if (hasNext && sact) {
        float4* dst = (float4*)&wbuf[wcur ^ 1][sciL][spp][0];
        dst[0] = q0; dst[1] = q1; dst[2] = q2; dst[3] = q3; dst[4] = q4;
      }
      if (half == 1 && more && pa) {
#pragma unroll
        for (int ci = 0; ci < CHUNK; ++ci)
          tile[1 - cur][ci][prow + 1][pcol + 1] = v[ci];
      }
      __syncthreads();
      wcur ^= 1;
    }
  }

  if (ract) {
#pragma unroll
    for (int g = 0; g < NP; ++g) {
      const int ocx = 32 * g + col;
      const int ocy = ocx + 16;
      float* opx = po + (size_t)s * sStride + ((size_t)b * Cout + co0 + ocx) * 196 + r * 14;
      float* opy = po + (size_t)s * sStride + ((size_t)b * Cout + co0 + ocy) * 196 + r * 14;
#pragma unroll
      for (int j = 0; j < 14; ++j) { opx[j] = acc[g][j].x; opy[j] = acc[g][j].y; }
    }
  }
}

// ---------------- combine partials + bias + GELU + GroupNorm (conv2/conv3) ----------------
template<int S>
__global__ __launch_bounds__(256) void combine_gn(
    const float* __restrict__ po0, const float* __restrict__ po1,
    const float* __restrict__ bs0, const float* __restrict__ bs1,
    const float* __restrict__ gw0, const float* __restrict__ gw1,
    const float* __restrict__ gb0, const float* __restrict__ gb1,
    float* __restrict__ out0, float* __restrict__ out1,
    int Cout, int cobPerHead, size_t sStride)
{
  const int tid = threadIdx.x, bx = blockIdx.x, b = blockIdx.y;
  const int head = bx / cobPerHead, cob = bx - head * cobPerHead;
  const float* po = head ? po1 : po0;
  const float* bs = head ? bs1 : bs0;
  const float* gw = head ? gw1 : gw0;
  const float* gb = head ? gb1 : gb0;
  float* out      = head ? out1 : out0;
  const int co0 = cob * 16;

  __shared__ float red[4][4];
  __shared__ float stats[4];

  const int p = tid;
  const bool pa = p < 196;
  float v[16];
  float s0 = 0.f, q0 = 0.f, s1 = 0.f, q1 = 0.f;
  if (pa) {
#pragma unroll
    for (int c = 0; c < 16; ++c) {
      const size_t base = ((size_t)b * Cout + co0 + c) * 196 + p;
      float x = bs[co0 + c];
#pragma unroll
      for (int s = 0; s < S; ++s) x += po[base + (size_t)s * sStride];
      float g = 0.5f * x * (1.0f + erff(x * 0.70710678118654752440f));
      v[c] = g;
      if (c < 8) { s0 += g; q0 += g * g; } else { s1 += g; q1 += g * g; }
    }
  }
#pragma unroll
  for (int off = 32; off > 0; off >>= 1) {
    s0 += __shfl_down(s0, off, 64); q0 += __shfl_down(q0, off, 64);
    s1 += __shfl_down(s1, off, 64); q1 += __shfl_down(q1, off, 64);
  }
  const int wave = tid >> 6, lane = tid & 63;
  if (lane == 0) { red[wave][0] = s0; red[wave][1] = q0; red[wave][2] = s1; red[wave][3] = q1; }
  __syncthreads();
  if (tid == 0) {
    float S0 = red[0][0] + red[1][0] + red[2][0] + red[3][0];
    float Q0 = red[0][1] + red[1][1] + red[2][1] + red[3][1];
    float S1 = red[0][2] + red[1][2] + red[2][2] + red[3][2];
    float Q1 = red[0][3] + red[1][3] + red[2][3] + red[3][3];
    float m0 = S0 * (1.0f / 1568.0f);
    float v0 = Q0 * (1.0f / 1568.0f) - m0 * m0;
    float m1 = S1 * (1.0f / 1568.0f);
    float v1 = Q1 * (1.0f / 1568.0f) - m1 * m1;
    stats[0] = m0; stats[1] = 1.0f / sqrtf(v0 + 1e-5f);
    stats[2] = m1; stats[3] = 1.0f / sqrtf(v1 + 1e-5f);
  }
  __syncthreads();
  if (pa) {
    float m0 = stats[0], i0 = stats[1], m1 = stats[2], i1 = stats[3];
#pragma unroll
    for (int c = 0; c < 16; ++c) {
      float m  = (c < 8) ? m0 : m1;
      float iv = (c < 8) ? i0 : i1;
      float y = (v[c] - m) * iv * gw[co0 + c] + gb[co0 + c];
      out[((size_t)b * Cout + co0 + c) * 196 + p] = y;
    }
  }
}

// ---------------- fused 1x1 heads + per-image greedy NMS (R16) ----------------
__global__ __launch_bounds__(512) void nms_kernel(
  const float* __restrict__ tb, const float* __restrict__ tc,
  const float* __restrict__ wtb, const float* __restrict__ wtc,
  const float* __restrict__ bb,  const float* __restrict__ bc,
  float* __restrict__ bbox, float* __restrict__ out)
{
  const int b = blockIdx.x, tid = threadIdx.x;
  __shared__ unsigned long long key[SORTN];
  __shared__ float sx1[NN], sy1[NN], sx2[NN], sy2[NN], sar[NN], ssc[NN];
  __shared__ unsigned char sup[NN];
  __shared__ int sV, sMin;

  if (tid == 0) sV = 0;
  for (int i = NN + tid; i < SORTN; i += 512) key[i] = 0ull;

  int cntv = 0;
  if (tid < 196) {
    const int p = tid;
    float ab[36], ac[9];
#pragma unroll
    for (int o = 0; o < 36; ++o) ab[o] = bb[o];
#pragma unroll
    for (int o = 0; o < 9; ++o)  ac[o] = bc[o];
    const float* pb = tb + (size_t)b * 128 * 196 + p;
    const float* pc = tc + (size_t)b * 128 * 196 + p;
    for (int ci = 0; ci < 128; ++ci) {
      float xb = pb[ci * 196];
      float xc = pc[ci * 196];
      const float* wB = wtb + ci * 36;
      const float* wC = wtc + ci * 9;
#pragma unroll
      for (int o = 0; o < 36; ++o) ab[o] = fmaf(wB[o], xb, ab[o]);
#pragma unroll
      for (int o = 0; o < 9; ++o)  ac[o] = fmaf(wC[o], xc, ac[o]);
    }
    float* bp = bbox + ((size_t)b * NN) * 4 + (size_t)p * 36;
#pragma unroll
    for (int o = 0; o < 36; ++o) bp[o] = ab[o];
#pragma unroll
    for (int a = 0; a < 9; ++a) {
      float s = 1.0f / (1.0f + expf(-ac[a]));
      const int n = p * 9 + a;
      unsigned rank = (unsigned)(NN - 1 - n);
      unsigned long long k;
      if (s > 0.5f) { k = (((unsigned long long)__float_as_uint(s)) << 32) | rank; cntv++; }
      else k = (unsigned long long)rank;
      key[n] = k;
    }
  }
  atomicAdd(&sV, cntv);
  __syncthreads();
  const int V = sV;

  for (int kk = 2; kk <= SORTN; kk <<= 1) {
    for (int j = kk >> 1; j > 0; j >>= 1) {
      for (int i = tid; i < SORTN; i += 512) {
        int ixj = i ^ j;
        if (ixj > i) {
          unsigned long long a = key[i], c = key[ixj];
          bool dirDesc = ((i & kk) == 0);
          if ((a < c) == dirDesc) { key[i] = c; key[ixj] = a; }
        }
      }
      __syncthreads();
    }
  }

  const float* bbb = bbox + (size_t)b * NN * 4;
  for (int i = tid; i < V; i += 512) {
    unsigned long long k = key[i];
    int idx = NN - 1 - (int)(unsigned)(k & 0xFFFFFFFFull);
    float s = __uint_as_float((unsigned)(k >> 32));
    const float* bp = bbb + (size_t)idx * 4;
    float x1 = fminf(fmaxf(bp[0], 0.0f), 1.0f);
    float y1 = fminf(fmaxf(bp[1], 0.0f), 1.0f);
    float x2 = fminf(fmaxf(bp[2], 0.0f), 1.0f);
    float y2 = fminf(fmaxf(bp[3], 0.0f), 1.0f);
    sx1[i] = x1; sy1[i] = y1; sx2[i] = x2; sy2[i] = y2;
    sar[i] = (x2 - x1) * (y2 - y1);
    ssc[i] = s;
    sup[i] = 0;
  }
  __syncthreads();

  int kept = 0, cur = 0;
  float* ob = out + (size_t)b * 50 * 5;
  while (kept < 50 && cur < V) {
    int nxt = -1;
    for (int base = cur; base < V; base += 512) {
      if (tid == 0) sMin = 0x7FFFFFFF;
      __syncthreads();
      int i = base + tid;
      if (i < V && !sup[i]) atomicMin(&sMin, i);
      __syncthreads();
      if (sMin != 0x7FFFFFFF) { nxt = sMin; break; }
    }
    if (nxt < 0) break;
    float kx1 = sx1[nxt], ky1 = sy1[nxt], kx2 = sx2[nxt], ky2 = sy2[nxt], ka = sar[nxt];
    if (tid == 0) {
      float* rr = ob + kept * 5;
      rr[0] = kx1; rr[1] = ky1; rr[2] = kx2; rr[3] = ky2; rr[4] = ssc[nxt];
    }
    kept++;
    for (int jj = nxt + 1 + tid; jj < V; jj += 512) {
      if (!sup[jj]) {
        float xx1 = fmaxf(kx1, sx1[jj]);
        float yy1 = fmaxf(ky1, sy1[jj]);
        float xx2 = fminf(kx2, sx2[jj]);
        float yy2 = fminf(ky2, sy2[jj]);
        float inter = fmaxf(xx2 - xx1, 0.0f) * fmaxf(yy2 - yy1, 0.0f);
        float iou = inter / ((ka + sar[jj]) - inter);
        if (!(iou < 0.3f)) sup[jj] = 1;
      }
    }
    cur = nxt + 1;
    __syncthreads();
  }
  for (int rr = kept + tid; rr < 50; rr += 512) {
    float* qq = ob + rr * 5;
    qq[0] = 0.0f; qq[1] = 0.0f; qq[2] = 0.0f; qq[3] = 0.0f; qq[4] = -1.0f;
  }
}

// ---------------- launch ----------------
extern "C" void kernel_launch(void* const* d_in, const int* in_sizes, int n_in,
                              void* d_out, int out_size, void* d_ws, size_t ws_size,
                              hipStream_t stream)
{
  const float* features = (const float*)d_in[0];
  const float* b1w = (const float*)d_in[1];  const float* b1b = (const float*)d_in[2];
  const float* bg1w = (const float*)d_in[3]; const float* bg1b = (const float*)d_in[4];
  const float* b2w = (const float*)d_in[5];  const float* b2b = (const float*)d_in[6];
  const float* bg2w = (const float*)d_in[7]; const float* bg2b = (const float*)d_in[8];
  const float* b3w = (const float*)d_in[9];  const float* b3b = (const float*)d_in[10];
  const float* bg3w = (const float*)d_in[11]; const float* bg3b = (const float*)d_in[12];
  const float* b4w = (const float*)d_in[13]; const float* b4b = (const float*)d_in[14];
  const float* c1w = (const float*)d_in[15]; const float* c1b = (const float*)d_in[16];
  const float* cg1w = (const float*)d_in[17]; const float* cg1b = (const float*)d_in[18];
  const float* c2w = (const float*)d_in[19]; const float* c2b = (const float*)d_in[20];
  const float* cg2w = (const float*)d_in[21]; const float* cg2b = (const float*)d_in[22];
  const float* c3w = (const float*)d_in[23]; const float* c3b = (const float*)d_in[24];

  float* ws = (float*)d_ws;
  float* U    = ws; ws += 4194304;   // conv1 wino U: 2 heads x 16 x 512 x 256
  float* wp2b = ws; ws += 327680;
  float* wp2c = ws; ws += 327680;
  float* wp3b = ws; ws += 163840;
  float* wt4b = ws; ws += 4608;
  float* wt3c = ws; ws += 1152;
  float* t1b  = ws; ws += 1605632;   // 32*256*196
  float* t1c  = ws; ws += 1605632;
  float* t2b  = ws; ws += 802816;    // 32*128*196
  float* t2c  = ws; ws += 802816;
  float* V    = ws; ws += 12845056;  // wino V: 16 x 512 x 1568
  float* M    = ws; ws += 12845056;  // wino M: 2 heads x 16 x 256 x 1568
  float* bbox = ws; ws += 225792;
  float* P    = V;                   // conv2/conv3 partials alias V (dead after gemm)
  float* t3b  = t1b;                 // alias: t1b dead after conv2 reads it

  wtrans_all<<<3927, 256, 0, stream>>>(b1w, c1w, b2w, c2w, b3w, b4w, c3w,
                                       U, U + 2097152, wp2b, wp2c, wp3b, wt4b, wt3c);

  // conv1 via Winograd F(2,3): transform -> 16x2 GEMMs -> inverse transform + GN
  wino_in<<<dim3(32, 128), 256, 0, stream>>>(features, V);
  wino_gemm<<<dim3(16, 25, 4), 256, 0, stream>>>(V, U, M);
  wino_out_gn<<<dim3(32, 32), 256, 0, stream>>>(M, b1b, c1b, bg1w, cg1w, bg1b, cg1b, t1b, t1c);

  // conv2: Cin=256, Cout=128, COPT=4, S=4 -> 512 blocks, nch=4 (direct path)
  {
    const size_t sStr = (size_t)32 * 128 * 196;          // 802816
    conv3x3_part<4><<<dim3(4, 32, 4), 256, 0, stream>>>(
        t1b, t1c, wp2b, wp2c, P, P + 4 * sStr, 256, 128, 2, 64, sStr);
    combine_gn<4><<<dim3(16, 32), 256, 0, stream>>>(
        P, P + 4 * sStr, b2b, c2b, bg2w, cg2w, bg2b, cg2b, t2b, t2c, 128, 8, sStr);
  }
  // conv3 (bbox only): Cin=128, Cout=128, COPT=2, S=4 -> 512 blocks, nch=2
  {
    const size_t sStr = (size_t)32 * 128 * 196;
    conv3x3_part<2><<<dim3(4, 32, 4), 256, 0, stream>>>(
        t2b, t2b, wp3b, wp3b, P, P, 128, 128, 4, 32, sStr);
    combine_gn<4><<<dim3(8, 32), 256, 0, stream>>>(
        P, P, b3b, b3b, bg3w, bg3w, bg3b, bg3b, t3b, t3b, 128, 8, sStr);
  }

  nms_kernel<<<32, 512, 0, stream>>>(t3b, t2c, wt4b, wt3c, b4b, c3b, bbox, (float*)d_out);
}

// Round 14
// 650.406 us; speedup vs baseline: 1.0761x; 1.0761x over previous
//
#include <hip/hip_runtime.h>
#include <hip/hip_bf16.h>
#include <math.h>

#define CHUNK 16
#define NN 1764
#define SORTN 2048

typedef float v2f __attribute__((ext_vector_type(2)));

// async global->LDS, 16B per lane. LDS arg must be wave-uniform base; HW adds lane*16.
__device__ inline void gl_lds16(const float* g, float* l) {
  __builtin_amdgcn_global_load_lds(
      (const __attribute__((address_space(1))) void*)g,
      (__attribute__((address_space(3))) void*)l, 16, 0, 0);
}

// ---------------- weight packing ----------------
// Direct-conv packing (conv2/conv3): W[co][ci][3][3] -> Wpk[ci][p][20],
// pair p=(co>>5)*16+(co&15), h=(co&31)>>4 -> slot 2*k+h.
template<int Co, int Ci>
__device__ inline void seg_pack_pk(const float* __restrict__ src, float* __restrict__ dst, int i) {
  int co = i / (Ci * 9); int rem = i - co * (Ci * 9); int ci = rem / 9; int k = rem - ci * 9;
  int p = (co >> 5) * 16 + (co & 15);
  int h = (co & 31) >> 4;
  dst[((size_t)ci * (Co >> 1) + p) * 20 + 2 * k + h] = src[i];
}
template<int Co, int CiK>
__device__ inline void seg_tr(const float* __restrict__ src, float* __restrict__ dst, int i) {
  int co = i / CiK; int cik = i - co * CiK;
  dst[cik * Co + co] = src[i];
}

// R17/R22: Winograd F(2,3) weight transform for conv1.
// U = G g G^T (exact fp32). R22 layout: the 4 u2 fragments for one col are 8
// CONSECUTIVE floats (2x ds_read_b128, 2-way bank alias = free); LDS staging
// stays a LINEAR copy (global_load_lds compatible).
__device__ inline void seg_wino_u(const float* __restrict__ src, float* __restrict__ dst, int i) {
  int ci = i >> 8;            // i = ci*256 + co
  int co = i & 255;
  const float* g = src + ((size_t)co * 512 + ci) * 9;
  float g00=g[0],g01=g[1],g02=g[2],g10=g[3],g11=g[4],g12=g[5],g20=g[6],g21=g[7],g22=g[8];
  float a[4][3];
  a[0][0]=g00; a[0][1]=g01; a[0][2]=g02;
  a[1][0]=0.5f*(g00+g10+g20); a[1][1]=0.5f*(g01+g11+g21); a[1][2]=0.5f*(g02+g12+g22);
  a[2][0]=0.5f*(g00-g10+g20); a[2][1]=0.5f*(g01-g11+g21); a[2][2]=0.5f*(g02-g12+g22);
  a[3][0]=g20; a[3][1]=g21; a[3][2]=g22;
  const int p_old = (co >> 5) * 16 + (co & 15);
  const int h = (co & 31) >> 4;
  const int pb = p_old >> 6, loc = p_old & 63;
  const int gg = loc >> 4, col = loc & 15;
  const int P = pb * 64 + (gg >> 1) * 32 + col * 2 + (gg & 1);
#pragma unroll
  for (int r4 = 0; r4 < 4; ++r4) {
    float u0 = a[r4][0];
    float u1 = 0.5f * (a[r4][0] + a[r4][1] + a[r4][2]);
    float u2 = 0.5f * (a[r4][0] - a[r4][1] + a[r4][2]);
    float u3 = a[r4][2];
    float uv[4] = {u0, u1, u2, u3};
#pragma unroll
    for (int c4 = 0; c4 < 4; ++c4) {
      int pos = r4 * 4 + c4;
      dst[(((size_t)pos * 512 + ci) * 128 + P) * 2 + h] = uv[c4];
    }
  }
}

// R24: wtrans_all and wino_in fused — fully independent work (weights->U/wp*,
// features->V, disjoint outputs), was two serial launches (~55us); co-scheduled
// in one grid. Blocks [0,3927) = weight transforms; [3927, 8023) = wino_in.
__global__ void wtrans_wino_in(
  const float* __restrict__ b1w, const float* __restrict__ c1w,
  const float* __restrict__ b2w, const float* __restrict__ c2w,
  const float* __restrict__ b3w, const float* __restrict__ b4w,
  const float* __restrict__ c3w, const float* __restrict__ features,
  float* __restrict__ ub, float* __restrict__ uc,
  float* __restrict__ wp2b, float* __restrict__ wp2c,
  float* __restrict__ wp3b, float* __restrict__ wt4b, float* __restrict__ wt3c,
  float* __restrict__ V)
{
  const int bx = blockIdx.x;
  if (bx < 3927) {
    int j = bx * 256 + threadIdx.x;
    if (j < 131072) { seg_wino_u(b1w, ub, j); return; } j -= 131072;
    if (j < 131072) { seg_wino_u(c1w, uc, j); return; } j -= 131072;
    if (j < 294912) { seg_pack_pk<128, 256>(b2w, wp2b, j); return; } j -= 294912;
    if (j < 294912) { seg_pack_pk<128, 256>(c2w, wp2c, j); return; } j -= 294912;
    if (j < 147456) { seg_pack_pk<128, 128>(b3w, wp3b, j); return; } j -= 147456;
    if (j < 4608)   { seg_tr<36, 128>(b4w, wt4b, j); return; }  j -= 4608;
    if (j < 1152)   { seg_tr<9, 128>(c3w, wt3c, j); return; }
    return;
  }
  // ---- wino_in part: V = B^T d B per (b, ci, tile) ----
  const int idx = bx - 3927;            // 0..4095
  const int b = idx >> 7, cig = idx & 127;
  const int tid = threadIdx.x;
  if (tid >= 196) return;
  const int ci = cig * 4 + tid / 49;
  const int t  = tid % 49;
  const int ty = t / 7, tx = t % 7;
  const float* fp = features + ((size_t)b * 512 + ci) * 196;
  const int y0 = 2 * ty - 1, x0 = 2 * tx - 1;
  float d[4][4];
#pragma unroll
  for (int i = 0; i < 4; ++i) {
    const int y = y0 + i;
#pragma unroll
    for (int j = 0; j < 4; ++j) {
      const int x = x0 + j;
      d[i][j] = (y >= 0 && y < 14 && x >= 0 && x < 14) ? fp[y * 14 + x] : 0.0f;
    }
  }
  float tr[4][4];
#pragma unroll
  for (int j = 0; j < 4; ++j) {
    tr[0][j] = d[0][j] - d[2][j];
    tr[1][j] = d[1][j] + d[2][j];
    tr[2][j] = d[2][j] - d[1][j];
    tr[3][j] = d[1][j] - d[3][j];
  }
  const size_t m = (size_t)b * 49 + t;
#pragma unroll
  for (int i = 0; i < 4; ++i) {
    float v0 = tr[i][0] - tr[i][2];
    float v1 = tr[i][1] + tr[i][2];
    float v2 = tr[i][2] - tr[i][1];
    float v3 = tr[i][1] - tr[i][3];
    V[((size_t)(i * 4 + 0) * 512 + ci) * 1568 + m] = v0;
    V[((size_t)(i * 4 + 1) * 512 + ci) * 1568 + m] = v1;
    V[((size_t)(i * 4 + 2) * 512 + ci) * 1568 + m] = v2;
    V[((size_t)(i * 4 + 3) * 512 + ci) * 1568 + m] = v3;
  }
}

// ---------------- R22: Winograd GEMM (global_load_lds staging + b128 u-reads) ----------------
// LEDGER: 16-ci phase / 4x4 tile / (256,2) is the ONLY spill-free config.
//   R19 (32-ci), R20 (3 waves, reg-staged), R23 (3 waves, gl_lds) all spilled.
//   Occupancy and phase-depth levers permanently closed.
// R22 analysis: kernel is ~75% LDS-pipe-bound (48 b128-reads/thread/phase is
//   data-volume-fixed by the register-capped tile) -> ~216us is this family's
//   floor. VALUBusy 50, bank-conflicts 0, WRITE=50MB.
__global__ __launch_bounds__(256, 2) void wino_gemm(
    const float* __restrict__ V, const float* __restrict__ U, float* __restrict__ M)
{
  const int pos = blockIdx.x;     // 0..15
  const int mb  = blockIdx.y;     // 0..24
  const int q   = blockIdx.z;     // 0..3
  const int head = q >> 1;
  const int pb   = q & 1;
  const int tid = threadIdx.x;
  const int col = tid & 15;
  const int r   = tid >> 4;
  const int wv  = tid >> 6;       // wave id (LDS base must be wave-uniform)

  __shared__ float vbuf[2][16][64];    // 8 KB  (linear: buf*1024 + tid*4 floats)
  __shared__ float ubuf[2][16][128];   // 16 KB (linear: buf*2048 + k*1024 + tid*4)

  const float* Uh = U + (size_t)head * 2097152;
  float* Mh = M + (size_t)head * 6422528;
  const int m0 = mb * 64;

  // per-lane global sources (lane tid writes LDS float offset tid*4)
  const float* vg  = V + ((size_t)pos * 512 + (tid >> 4)) * 1568 + m0 + (tid & 15) * 4;
  const int c1 = 256 + tid;
  const float* ug0 = Uh + ((size_t)pos * 512 + (tid >> 5)) * 256 + pb * 128 + (tid & 31) * 4;
  const float* ug1 = Uh + ((size_t)pos * 512 + (c1 >> 5)) * 256 + pb * 128 + (c1 & 31) * 4;
  // wave-uniform LDS bases
  float* vls = ((float*)vbuf) + wv * 256;
  float* uls = ((float*)ubuf) + wv * 256;

  // prologue: stage cb=0 into buffer 0
  gl_lds16(vg, vls);
  gl_lds16(ug0, uls);
  gl_lds16(ug1, uls + 1024);
  __syncthreads();   // implicit vmcnt(0) drain

  v2f acc[4][4];
#pragma unroll
  for (int g = 0; g < 4; ++g)
#pragma unroll
    for (int j = 0; j < 4; ++j) acc[g][j] = (v2f)(0.0f);

  int cur = 0;
  for (int cb = 0; cb < 32; ++cb) {
    // issue next phase's async loads; they fly during this phase's compute
    if (cb + 1 < 32) {
      const int nb = cur ^ 1;
      gl_lds16(vg + (size_t)(cb + 1) * 16 * 1568, vls + nb * 1024);
      gl_lds16(ug0 + (size_t)(cb + 1) * 16 * 256, uls + nb * 2048);
      gl_lds16(ug1 + (size_t)(cb + 1) * 16 * 256, uls + nb * 2048 + 1024);
    }
#pragma unroll
    for (int ci = 0; ci < 16; ++ci) {
      const float4* uq0 = (const float4*)&ubuf[cur][ci][col * 4];        // g0,g1
      const float4* uq1 = (const float4*)&ubuf[cur][ci][64 + col * 4];   // g2,g3
      float4 a = uq0[0], bq = uq1[0];
      v2f u2[4] = { (v2f){a.x, a.y}, (v2f){a.z, a.w},
                    (v2f){bq.x, bq.y}, (v2f){bq.z, bq.w} };
      const float4* vp = (const float4*)&vbuf[cur][ci][r * 4];
      float4 v0 = vp[0];
      float vv[4] = {v0.x, v0.y, v0.z, v0.w};
#pragma unroll
      for (int j = 0; j < 4; ++j) {
        v2f s2 = (v2f){vv[j], vv[j]};
#pragma unroll
        for (int g = 0; g < 4; ++g)
          acc[g][j] = __builtin_elementwise_fma(u2[g], s2, acc[g][j]);
      }
    }
    __syncthreads();   // drains vmcnt (next-buffer loads) + all reads done
    cur ^= 1;
  }

  const int mm = m0 + r * 4;
  if (mm < 1568) {
#pragma unroll
    for (int g = 0; g < 4; ++g) {
      const int p = pb * 64 + g * 16 + col;
      const int cox = (p >> 4) * 32 + (p & 15);
      float* ox = Mh + ((size_t)pos * 256 + cox) * 1568 + mm;
      float* oy = ox + (size_t)16 * 1568;
#pragma unroll
      for (int j = 0; j < 4; ++j) { ox[j] = acc[g][j].x; oy[j] = acc[g][j].y; }
    }
  }
}

// ---------------- R17: Winograd output transform + bias + GELU + GN (conv1) ----------------
__global__ __launch_bounds__(256) void wino_out_gn(
    const float* __restrict__ M,
    const float* __restrict__ bsb, const float* __restrict__ bsc,
    const float* __restrict__ gwb, const float* __restrict__ gwc,
    const float* __restrict__ gbb, const float* __restrict__ gbc,
    float* __restrict__ outb, float* __restrict__ outc)
{
  const int bx = blockIdx.x;           // 0..31: head = bx>>4, cog = bx&15
  const int b  = blockIdx.y;
  const int head = bx >> 4, cog = bx & 15;
  const int tid = threadIdx.x;
  const float* Mh = M + (size_t)head * 6422528;
  const float* bs = head ? bsc : bsb;
  const float* gw = head ? gwc : gwb;
  const float* gb = head ? gbc : gbb;
  float* out      = head ? outc : outb;
  const int co0 = cog * 16;

  __shared__ float red[4][4];
  __shared__ float stats[4];

  const bool pa = tid < 196;
  const int csub = tid / 49;
  const int t    = tid % 49;
  const int ty = t / 7, tx = t % 7;
  const size_t mt = (size_t)b * 49 + t;

  float y4[4][4];
  float s = 0.f, q = 0.f;
  if (pa) {
#pragma unroll
    for (int cc = 0; cc < 4; ++cc) {
      const int co = co0 + csub * 4 + cc;
      const float* mp = Mh + (size_t)co * 1568 + mt;
      float m16[16];
#pragma unroll
      for (int pos = 0; pos < 16; ++pos)
        m16[pos] = mp[(size_t)pos * 401408];
      float Z0[4], Z1[4];
#pragma unroll
      for (int j = 0; j < 4; ++j) {
        Z0[j] = m16[0 * 4 + j] + m16[1 * 4 + j] + m16[2 * 4 + j];
        Z1[j] = m16[1 * 4 + j] - m16[2 * 4 + j] - m16[3 * 4 + j];
      }
      const float bias = bs[co];
      float yv[4];
      yv[0] = Z0[0] + Z0[1] + Z0[2];
      yv[1] = Z0[1] - Z0[2] - Z0[3];
      yv[2] = Z1[0] + Z1[1] + Z1[2];
      yv[3] = Z1[1] - Z1[2] - Z1[3];
#pragma unroll
      for (int k = 0; k < 4; ++k) {
        float x = yv[k] + bias;
        float g = 0.5f * x * (1.0f + erff(x * 0.70710678118654752440f));
        y4[cc][k] = g;
        s += g; q += g * g;
      }
    }
  }
  float s0 = (pa && csub < 2) ? s : 0.f, q0 = (pa && csub < 2) ? q : 0.f;
  float s1 = (pa && csub >= 2) ? s : 0.f, q1 = (pa && csub >= 2) ? q : 0.f;
#pragma unroll
  for (int off = 32; off > 0; off >>= 1) {
    s0 += __shfl_down(s0, off, 64); q0 += __shfl_down(q0, off, 64);
    s1 += __shfl_down(s1, off, 64); q1 += __shfl_down(q1, off, 64);
  }
  const int wave = tid >> 6, lane = tid & 63;
  if (lane == 0) { red[wave][0] = s0; red[wave][1] = q0; red[wave][2] = s1; red[wave][3] = q1; }
  __syncthreads();
  if (tid == 0) {
    float S0 = red[0][0] + red[1][0] + red[2][0] + red[3][0];
    float Q0 = red[0][1] + red[1][1] + red[2][1] + red[3][1];
    float S1 = red[0][2] + red[1][2] + red[2][2] + red[3][2];
    float Q1 = red[0][3] + red[1][3] + red[2][3] + red[3][3];
    float m0 = S0 * (1.0f / 1568.0f);
    float v0 = Q0 * (1.0f / 1568.0f) - m0 * m0;
    float m1 = S1 * (1.0f / 1568.0f);
    float v1 = Q1 * (1.0f / 1568.0f) - m1 * m1;
    stats[0] = m0; stats[1] = 1.0f / sqrtf(v0 + 1e-5f);
    stats[2] = m1; stats[3] = 1.0f / sqrtf(v1 + 1e-5f);
  }
  __syncthreads();
  if (pa) {
    const float mg = (csub < 2) ? stats[0] : stats[2];
    const float iv = (csub < 2) ? stats[1] : stats[3];
#pragma unroll
    for (int cc = 0; cc < 4; ++cc) {
      const int co = co0 + csub * 4 + cc;
      const float w = gw[co], bb2 = gb[co];
      float* op = out + ((size_t)b * 256 + co) * 196;
#pragma unroll
      for (int dy = 0; dy < 2; ++dy)
#pragma unroll
        for (int dx = 0; dx < 2; ++dx) {
          float yv = (y4[cc][dy * 2 + dx] - mg) * iv * w + bb2;
          op[(2 * ty + dy) * 14 + (2 * tx + dx)] = yv;
        }
    }
  }
}

// ---------------- split-K partial conv3x3 (conv2/conv3 direct path) ----------------
// NOTE (R10): MFMA/bf16 conv precision-blocked; keep fp32.
// NOTE (R11-R16): ILP/occupancy/setprio all null; LDS-staged weights (R14) and
//   1-barrier dbuf (R15) are load-bearing. Structure ceiling ~59% fp32 ALU.
template<int COPT>
__global__ __launch_bounds__(256, 2) void conv3x3_part(
    const float* __restrict__ in0, const float* __restrict__ in1,
    const float* __restrict__ wt0, const float* __restrict__ wt1,
    float* __restrict__ po0, float* __restrict__ po1,
    int Cin, int Cout, int cobPerHead, int cinPerSplit, size_t sStride)
{
  constexpr int NP = COPT / 2;
  constexpr int NPP = 16 * NP;
  constexpr int NPAIR = 8 * NPP;
  const int tid = threadIdx.x;
  const int bx  = blockIdx.x;
  const int b   = blockIdx.y;
  const int s   = blockIdx.z;
  const int head = bx / cobPerHead;
  const int cob  = bx - head * cobPerHead;
  const float* in  = head ? in1  : in0;
  const float* wt  = head ? wt1  : wt0;
  float* po        = head ? po1  : po0;
  const int co0 = cob * (16 * COPT);

  const int col = tid & 15;
  const int r   = tid >> 4;
  const bool ract = r < 14;

  __shared__ float tile[2][CHUNK][16][16];
  __shared__ float wbuf[2][8][NPP][20];

  {
    float* tz = &tile[0][0][0][0];
    for (int i = tid; i < 2 * CHUNK * 256; i += 256) tz[i] = 0.0f;
  }
  __syncthreads();

  const int p = tid;
  const bool pa = p < 196;
  const int prow = p / 14, pcol = p - prow * 14;
  const float* inb = in + (size_t)b * Cin * 196;
  const int cb0 = (s * cinPerSplit) / CHUNK;
  const int nch = cinPerSplit / CHUNK;
  const int CoutH = Cout >> 1;

  const int sciL = tid / NPP;
  const int spp  = tid - sciL * NPP;
  const bool sact = tid < NPAIR;
  const int spidx = ((co0 >> 5) + (spp >> 4)) * 16 + (spp & 15);

  if (pa) {
#pragma unroll
    for (int ci = 0; ci < CHUNK; ++ci)
      tile[0][ci][prow + 1][pcol + 1] = inb[(cb0 * CHUNK + ci) * 196 + p];
  }
  if (sact) {
    const float4* src = (const float4*)(wt + ((size_t)(cb0 * CHUNK + sciL) * CoutH + spidx) * 20);
    float4 q0 = src[0], q1 = src[1], q2 = src[2], q3 = src[3], q4 = src[4];
    float4* dst = (float4*)&wbuf[0][sciL][spp][0];
    dst[0] = q0; dst[1] = q1; dst[2] = q2; dst[3] = q3; dst[4] = q4;
  }
  __syncthreads();

  v2f acc[NP][14];
#pragma unroll
  for (int g = 0; g < NP; ++g)
#pragma unroll
    for (int j = 0; j < 14; ++j) acc[g][j] = (v2f)(0.0f);

  int wcur = 0;
  for (int lcb = 0; lcb < nch; ++lcb) {
    const int cbg = cb0 + lcb;
    const int cur = lcb & 1;
    const bool more = (lcb + 1 < nch);
    float v[CHUNK];
    if (more && pa) {
#pragma unroll
      for (int ci = 0; ci < CHUNK; ++ci)
        v[ci] = inb[((cbg + 1) * CHUNK + ci) * 196 + p];
    }
#pragma unroll
    for (int half = 0; half < 2; ++half) {
      const bool hasNext = (half == 0) || more;
      const int nbase = (half == 0) ? (cbg * CHUNK + 8) : ((cbg + 1) * CHUNK);
      float4 q0, q1, q2, q3, q4;
      if (hasNext && sact) {
        const float4* src = (const float4*)(wt + ((size_t)(nbase + sciL) * CoutH + spidx) * 20);
        q0 = src[0]; q1 = src[1]; q2 = src[2]; q3 = src[3]; q4 = src[4];
      }
      if (ract) {
#pragma unroll
        for (int ciL = 0; ciL < 8; ++ciL) {
          const int ci = half * 8 + ciL;
          v2f w2[NP][9];
#pragma unroll
          for (int g = 0; g < NP; ++g) {
            const float4* wq = (const float4*)&wbuf[wcur][ciL][g * 16 + col][0];
            float4 a0 = wq[0], a1 = wq[1], a2 = wq[2], a3 = wq[3], a4 = wq[4];
            w2[g][0] = (v2f){a0.x, a0.y}; w2[g][1] = (v2f){a0.z, a0.w};
            w2[g][2] = (v2f){a1.x, a1.y}; w2[g][3] = (v2f){a1.z, a1.w};
            w2[g][4] = (v2f){a2.x, a2.y}; w2[g][5] = (v2f){a2.z, a2.w};
            w2[g][6] = (v2f){a3.x, a3.y}; w2[g][7] = (v2f){a3.z, a3.w};
            w2[g][8] = (v2f){a4.x, a4.y};
          }
          float nb[3][16];
#pragma unroll
          for (int dr = 0; dr < 3; ++dr) {
            const float4* rp = (const float4*)(&tile[cur][ci][r + dr][0]);
            float4 a = rp[0], bq = rp[1], cq = rp[2], dq = rp[3];
            nb[dr][0]  = a.x;  nb[dr][1]  = a.y;  nb[dr][2]  = a.z;  nb[dr][3]  = a.w;
            nb[dr][4]  = bq.x; nb[dr][5]  = bq.y; nb[dr][6]  = bq.z; nb[dr][7]  = bq.w;
            nb[dr][8]  = cq.x; nb[dr][9]  = cq.y; nb[dr][10] = cq.z; nb[dr][11] = cq.w;
            nb[dr][12] = dq.x; nb[dr][13] = dq.y; nb[dr][14] = dq.z; nb[dr][15] = dq.w;
          }
#pragma unroll
          for (int ky = 0; ky < 3; ++ky)
#pragma unroll
            for (int kx = 0; kx < 3; ++kx) {
#pragma unroll
              for (int g = 0; g < NP; ++g) {
                v2f w = w2[g][ky * 3 + kx];
#pragma unroll
                for (int j = 0; j < 14; ++j) {
                  float s_ = nb[ky][j + kx];
                  v2f nbv = (v2f){s_, s_};
                  acc[g][j] = __builtin_elementwise_fma(w, nbv, acc[g][j]);
                }
              }
            }
        }
      }
      if (hasNext && sact) {
        float4* dst = (float4*)&wbuf[wcur ^ 1][sciL][spp][0];
        dst[0] = q0; dst[1] = q1; dst[2] = q2; dst[3] = q3; dst[4] = q4;
      }
      if (half == 1 && more && pa) {
#pragma unroll
        for (int ci = 0; ci < CHUNK; ++ci)
          tile[1 - cur][ci][prow + 1][pcol + 1] = v[ci];
      }
      __syncthreads();
      wcur ^= 1;
    }
  }

  if (ract) {
#pragma unroll
    for (int g = 0; g < NP; ++g) {
      const int ocx = 32 * g + col;
      const int ocy = ocx + 16;
      float* opx = po + (size_t)s * sStride + ((size_t)b * Cout + co0 + ocx) * 196 + r * 14;
      float* opy = po + (size_t)s * sStride + ((size_t)b * Cout + co0 + ocy) * 196 + r * 14;
#pragma unroll
      for (int j = 0; j < 14; ++j) { opx[j] = acc[g][j].x; opy[j] = acc[g][j].y; }
    }
  }
}

// ---------------- combine partials + bias + GELU + GroupNorm (conv2/conv3) ----------------
template<int S>
__global__ __launch_bounds__(256) void combine_gn(
    const float* __restrict__ po0, const float* __restrict__ po1,
    const float* __restrict__ bs0, const float* __restrict__ bs1,
    const float* __restrict__ gw0, const float* __restrict__ gw1,
    const float* __restrict__ gb0, const float* __restrict__ gb1,
    float* __restrict__ out0, float* __restrict__ out1,
    int Cout, int cobPerHead, size_t sStride)
{
  const int tid = threadIdx.x, bx = blockIdx.x, b = blockIdx.y;
  const int head = bx / cobPerHead, cob = bx - head * cobPerHead;
  const float* po = head ? po1 : po0;
  const float* bs = head ? bs1 : bs0;
  const float* gw = head ? gw1 : gw0;
  const float* gb = head ? gb1 : gb0;
  float* out      = head ? out1 : out0;
  const int co0 = cob * 16;

  __shared__ float red[4][4];
  __shared__ float stats[4];

  const int p = tid;
  const bool pa = p < 196;
  float v[16];
  float s0 = 0.f, q0 = 0.f, s1 = 0.f, q1 = 0.f;
  if (pa) {
#pragma unroll
    for (int c = 0; c < 16; ++c) {
      const size_t base = ((size_t)b * Cout + co0 + c) * 196 + p;
      float x = bs[co0 + c];
#pragma unroll
      for (int s = 0; s < S; ++s) x += po[base + (size_t)s * sStride];
      float g = 0.5f * x * (1.0f + erff(x * 0.70710678118654752440f));
      v[c] = g;
      if (c < 8) { s0 += g; q0 += g * g; } else { s1 += g; q1 += g * g; }
    }
  }
#pragma unroll
  for (int off = 32; off > 0; off >>= 1) {
    s0 += __shfl_down(s0, off, 64); q0 += __shfl_down(q0, off, 64);
    s1 += __shfl_down(s1, off, 64); q1 += __shfl_down(q1, off, 64);
  }
  const int wave = tid >> 6, lane = tid & 63;
  if (lane == 0) { red[wave][0] = s0; red[wave][1] = q0; red[wave][2] = s1; red[wave][3] = q1; }
  __syncthreads();
  if (tid == 0) {
    float S0 = red[0][0] + red[1][0] + red[2][0] + red[3][0];
    float Q0 = red[0][1] + red[1][1] + red[2][1] + red[3][1];
    float S1 = red[0][2] + red[1][2] + red[2][2] + red[3][2];
    float Q1 = red[0][3] + red[1][3] + red[2][3] + red[3][3];
    float m0 = S0 * (1.0f / 1568.0f);
    float v0 = Q0 * (1.0f / 1568.0f) - m0 * m0;
    float m1 = S1 * (1.0f / 1568.0f);
    float v1 = Q1 * (1.0f / 1568.0f) - m1 * m1;
    stats[0] = m0; stats[1] = 1.0f / sqrtf(v0 + 1e-5f);
    stats[2] = m1; stats[3] = 1.0f / sqrtf(v1 + 1e-5f);
  }
  __syncthreads();
  if (pa) {
    float m0 = stats[0], i0 = stats[1], m1 = stats[2], i1 = stats[3];
#pragma unroll
    for (int c = 0; c < 16; ++c) {
      float m  = (c < 8) ? m0 : m1;
      float iv = (c < 8) ? i0 : i1;
      float y = (v[c] - m) * iv * gw[co0 + c] + gb[co0 + c];
      out[((size_t)b * Cout + co0 + c) * 196 + p] = y;
    }
  }
}

// ---------------- fused 1x1 heads + per-image greedy NMS (R16) ----------------
__global__ __launch_bounds__(512) void nms_kernel(
  const float* __restrict__ tb, const float* __restrict__ tc,
  const float* __restrict__ wtb, const float* __restrict__ wtc,
  const float* __restrict__ bb,  const float* __restrict__ bc,
  float* __restrict__ bbox, float* __restrict__ out)
{
  const int b = blockIdx.x, tid = threadIdx.x;
  __shared__ unsigned long long key[SORTN];
  __shared__ float sx1[NN], sy1[NN], sx2[NN], sy2[NN], sar[NN], ssc[NN];
  __shared__ unsigned char sup[NN];
  __shared__ int sV, sMin;

  if (tid == 0) sV = 0;
  for (int i = NN + tid; i < SORTN; i += 512) key[i] = 0ull;

  int cntv = 0;
  if (tid < 196) {
    const int p = tid;
    float ab[36], ac[9];
#pragma unroll
    for (int o = 0; o < 36; ++o) ab[o] = bb[o];
#pragma unroll
    for (int o = 0; o < 9; ++o)  ac[o] = bc[o];
    const float* pb = tb + (size_t)b * 128 * 196 + p;
    const float* pc = tc + (size_t)b * 128 * 196 + p;
    for (int ci = 0; ci < 128; ++ci) {
      float xb = pb[ci * 196];
      float xc = pc[ci * 196];
      const float* wB = wtb + ci * 36;
      const float* wC = wtc + ci * 9;
#pragma unroll
      for (int o = 0; o < 36; ++o) ab[o] = fmaf(wB[o], xb, ab[o]);
#pragma unroll
      for (int o = 0; o < 9; ++o)  ac[o] = fmaf(wC[o], xc, ac[o]);
    }
    float* bp = bbox + ((size_t)b * NN) * 4 + (size_t)p * 36;
#pragma unroll
    for (int o = 0; o < 36; ++o) bp[o] = ab[o];
#pragma unroll
    for (int a = 0; a < 9; ++a) {
      float s = 1.0f / (1.0f + expf(-ac[a]));
      const int n = p * 9 + a;
      unsigned rank = (unsigned)(NN - 1 - n);
      unsigned long long k;
      if (s > 0.5f) { k = (((unsigned long long)__float_as_uint(s)) << 32) | rank; cntv++; }
      else k = (unsigned long long)rank;
      key[n] = k;
    }
  }
  atomicAdd(&sV, cntv);
  __syncthreads();
  const int V = sV;

  for (int kk = 2; kk <= SORTN; kk <<= 1) {
    for (int j = kk >> 1; j > 0; j >>= 1) {
      for (int i = tid; i < SORTN; i += 512) {
        int ixj = i ^ j;
        if (ixj > i) {
          unsigned long long a = key[i], c = key[ixj];
          bool dirDesc = ((i & kk) == 0);
          if ((a < c) == dirDesc) { key[i] = c; key[ixj] = a; }
        }
      }
      __syncthreads();
    }
  }

  const float* bbb = bbox + (size_t)b * NN * 4;
  for (int i = tid; i < V; i += 512) {
    unsigned long long k = key[i];
    int idx = NN - 1 - (int)(unsigned)(k & 0xFFFFFFFFull);
    float s = __uint_as_float((unsigned)(k >> 32));
    const float* bp = bbb + (size_t)idx * 4;
    float x1 = fminf(fmaxf(bp[0], 0.0f), 1.0f);
    float y1 = fminf(fmaxf(bp[1], 0.0f), 1.0f);
    float x2 = fminf(fmaxf(bp[2], 0.0f), 1.0f);
    float y2 = fminf(fmaxf(bp[3], 0.0f), 1.0f);
    sx1[i] = x1; sy1[i] = y1; sx2[i] = x2; sy2[i] = y2;
    sar[i] = (x2 - x1) * (y2 - y1);
    ssc[i] = s;
    sup[i] = 0;
  }
  __syncthreads();

  int kept = 0, cur = 0;
  float* ob = out + (size_t)b * 50 * 5;
  while (kept < 50 && cur < V) {
    int nxt = -1;
    for (int base = cur; base < V; base += 512) {
      if (tid == 0) sMin = 0x7FFFFFFF;
      __syncthreads();
      int i = base + tid;
      if (i < V && !sup[i]) atomicMin(&sMin, i);
      __syncthreads();
      if (sMin != 0x7FFFFFFF) { nxt = sMin; break; }
    }
    if (nxt < 0) break;
    float kx1 = sx1[nxt], ky1 = sy1[nxt], kx2 = sx2[nxt], ky2 = sy2[nxt], ka = sar[nxt];
    if (tid == 0) {
      float* rr = ob + kept * 5;
      rr[0] = kx1; rr[1] = ky1; rr[2] = kx2; rr[3] = ky2; rr[4] = ssc[nxt];
    }
    kept++;
    for (int jj = nxt + 1 + tid; jj < V; jj += 512) {
      if (!sup[jj]) {
        float xx1 = fmaxf(kx1, sx1[jj]);
        float yy1 = fmaxf(ky1, sy1[jj]);
        float xx2 = fminf(kx2, sx2[jj]);
        float yy2 = fminf(ky2, sy2[jj]);
        float inter = fmaxf(xx2 - xx1, 0.0f) * fmaxf(yy2 - yy1, 0.0f);
        float iou = inter / ((ka + sar[jj]) - inter);
        if (!(iou < 0.3f)) sup[jj] = 1;
      }
    }
    cur = nxt + 1;
    __syncthreads();
  }
  for (int rr = kept + tid; rr < 50; rr += 512) {
    float* qq = ob + rr * 5;
    qq[0] = 0.0f; qq[1] = 0.0f; qq[2] = 0.0f; qq[3] = 0.0f; qq[4] = -1.0f;
  }
}

// ---------------- launch ----------------
extern "C" void kernel_launch(void* const* d_in, const int* in_sizes, int n_in,
                              void* d_out, int out_size, void* d_ws, size_t ws_size,
                              hipStream_t stream)
{
  const float* features = (const float*)d_in[0];
  const float* b1w = (const float*)d_in[1];  const float* b1b = (const float*)d_in[2];
  const float* bg1w = (const float*)d_in[3]; const float* bg1b = (const float*)d_in[4];
  const float* b2w = (const float*)d_in[5];  const float* b2b = (const float*)d_in[6];
  const float* bg2w = (const float*)d_in[7]; const float* bg2b = (const float*)d_in[8];
  const float* b3w = (const float*)d_in[9];  const float* b3b = (const float*)d_in[10];
  const float* bg3w = (const float*)d_in[11]; const float* bg3b = (const float*)d_in[12];
  const float* b4w = (const float*)d_in[13]; const float* b4b = (const float*)d_in[14];
  const float* c1w = (const float*)d_in[15]; const float* c1b = (const float*)d_in[16];
  const float* cg1w = (const float*)d_in[17]; const float* cg1b = (const float*)d_in[18];
  const float* c2w = (const float*)d_in[19]; const float* c2b = (const float*)d_in[20];
  const float* cg2w = (const float*)d_in[21]; const float* cg2b = (const float*)d_in[22];
  const float* c3w = (const float*)d_in[23]; const float* c3b = (const float*)d_in[24];

  float* ws = (float*)d_ws;
  float* U    = ws; ws += 4194304;   // conv1 wino U: 2 heads x 16 x 512 x 256
  float* wp2b = ws; ws += 327680;
  float* wp2c = ws; ws += 327680;
  float* wp3b = ws; ws += 163840;
  float* wt4b = ws; ws += 4608;
  float* wt3c = ws; ws += 1152;
  float* t1b  = ws; ws += 1605632;   // 32*256*196
  float* t1c  = ws; ws += 1605632;
  float* t2b  = ws; ws += 802816;    // 32*128*196
  float* t2c  = ws; ws += 802816;
  float* V    = ws; ws += 12845056;  // wino V: 16 x 512 x 1568
  float* M    = ws; ws += 12845056;  // wino M: 2 heads x 16 x 256 x 1568
  float* bbox = ws; ws += 225792;
  float* P    = V;                   // conv2/conv3 partials alias V (dead after gemm)
  float* t3b  = t1b;                 // alias: t1b dead after conv2 reads it

  // R24: weight transforms + wino input transform fused (independent work)
  wtrans_wino_in<<<8023, 256, 0, stream>>>(b1w, c1w, b2w, c2w, b3w, b4w, c3w,
                                           features,
                                           U, U + 2097152, wp2b, wp2c, wp3b,
                                           wt4b, wt3c, V);

  // conv1 via Winograd F(2,3): 16x2 GEMMs -> inverse transform + GN
  wino_gemm<<<dim3(16, 25, 4), 256, 0, stream>>>(V, U, M);
  wino_out_gn<<<dim3(32, 32), 256, 0, stream>>>(M, b1b, c1b, bg1w, cg1w, bg1b, cg1b, t1b, t1c);

  // conv2: Cin=256, Cout=128, COPT=4, S=4 -> 512 blocks, nch=4 (direct path)
  {
    const size_t sStr = (size_t)32 * 128 * 196;          // 802816
    conv3x3_part<4><<<dim3(4, 32, 4), 256, 0, stream>>>(
        t1b, t1c, wp2b, wp2c, P, P + 4 * sStr, 256, 128, 2, 64, sStr);
    combine_gn<4><<<dim3(16, 32), 256, 0, stream>>>(
        P, P + 4 * sStr, b2b, c2b, bg2w, cg2w, bg2b, cg2b, t2b, t2c, 128, 8, sStr);
  }
  // conv3 (bbox only): Cin=128, Cout=128, COPT=2, S=4 -> 512 blocks, nch=2
  {
    const size_t sStr = (size_t)32 * 128 * 196;
    conv3x3_part<2><<<dim3(4, 32, 4), 256, 0, stream>>>(
        t2b, t2b, wp3b, wp3b, P, P, 128, 128, 4, 32, sStr);
    combine_gn<4><<<dim3(8, 32), 256, 0, stream>>>(
        P, P, b3b, b3b, bg3w, bg3w, bg3b, bg3b, t3b, t3b, 128, 8, sStr);
  }

  nms_kernel<<<32, 512, 0, stream>>>(t3b, t2c, wt4b, wt3c, b4b, c3b, bbox, (float*)d_out);
}

// Round 15
// 628.325 us; speedup vs baseline: 1.1139x; 1.0351x over previous
//
#include <hip/hip_runtime.h>
#include <hip/hip_bf16.h>
#include <math.h>

#define CHUNK 16
#define NN 1764
#define SORTN 2048

typedef float v2f __attribute__((ext_vector_type(2)));

// async global->LDS, 16B per lane. LDS arg must be wave-uniform base; HW adds lane*16.
__device__ inline void gl_lds16(const float* g, float* l) {
  __builtin_amdgcn_global_load_lds(
      (const __attribute__((address_space(1))) void*)g,
      (__attribute__((address_space(3))) void*)l, 16, 0, 0);
}

// ---------------- weight packing ----------------
// Direct-conv packing (conv3): W[co][ci][3][3] -> Wpk[ci][p][20].
template<int Co, int Ci>
__device__ inline void seg_pack_pk(const float* __restrict__ src, float* __restrict__ dst, int i) {
  int co = i / (Ci * 9); int rem = i - co * (Ci * 9); int ci = rem / 9; int k = rem - ci * 9;
  int p = (co >> 5) * 16 + (co & 15);
  int h = (co & 31) >> 4;
  dst[((size_t)ci * (Co >> 1) + p) * 20 + 2 * k + h] = src[i];
}
template<int Co, int CiK>
__device__ inline void seg_tr(const float* __restrict__ src, float* __restrict__ dst, int i) {
  int co = i / CiK; int cik = i - co * CiK;
  dst[cik * Co + co] = src[i];
}

// Winograd weight transform, conv1 (Cin=512, Cout=256). R22 layout: per ci-row
// (256 floats = 2 pb x 128), the 4 u2 frags for one col are 8 consecutive floats.
__device__ inline void seg_wino_u(const float* __restrict__ src, float* __restrict__ dst, int i) {
  int ci = i >> 8;            // i = ci*256 + co
  int co = i & 255;
  const float* g = src + ((size_t)co * 512 + ci) * 9;
  float g00=g[0],g01=g[1],g02=g[2],g10=g[3],g11=g[4],g12=g[5],g20=g[6],g21=g[7],g22=g[8];
  float a[4][3];
  a[0][0]=g00; a[0][1]=g01; a[0][2]=g02;
  a[1][0]=0.5f*(g00+g10+g20); a[1][1]=0.5f*(g01+g11+g21); a[1][2]=0.5f*(g02+g12+g22);
  a[2][0]=0.5f*(g00-g10+g20); a[2][1]=0.5f*(g01-g11+g21); a[2][2]=0.5f*(g02-g12+g22);
  a[3][0]=g20; a[3][1]=g21; a[3][2]=g22;
  const int p_old = (co >> 5) * 16 + (co & 15);
  const int h = (co & 31) >> 4;
  const int pb = p_old >> 6, loc = p_old & 63;
  const int gg = loc >> 4, col = loc & 15;
  const int P = pb * 64 + (gg >> 1) * 32 + col * 2 + (gg & 1);
#pragma unroll
  for (int r4 = 0; r4 < 4; ++r4) {
    float u0 = a[r4][0];
    float u1 = 0.5f * (a[r4][0] + a[r4][1] + a[r4][2]);
    float u2 = 0.5f * (a[r4][0] - a[r4][1] + a[r4][2]);
    float u3 = a[r4][2];
    float uv[4] = {u0, u1, u2, u3};
#pragma unroll
    for (int c4 = 0; c4 < 4; ++c4) {
      int pos = r4 * 4 + c4;
      dst[(((size_t)pos * 512 + ci) * 128 + P) * 2 + h] = uv[c4];
    }
  }
}

// R25: Winograd weight transform, conv2 (Cin=256, Cout=128). Row = 128 floats,
// same within-row layout (no pb): P = (gg>>1)*32 + col*2 + (gg&1).
__device__ inline void seg_wino_u2(const float* __restrict__ src, float* __restrict__ dst, int i) {
  int ci = i >> 7;            // i = ci*128 + co, ci in 0..255
  int co = i & 127;
  const float* g = src + ((size_t)co * 256 + ci) * 9;
  float g00=g[0],g01=g[1],g02=g[2],g10=g[3],g11=g[4],g12=g[5],g20=g[6],g21=g[7],g22=g[8];
  float a[4][3];
  a[0][0]=g00; a[0][1]=g01; a[0][2]=g02;
  a[1][0]=0.5f*(g00+g10+g20); a[1][1]=0.5f*(g01+g11+g21); a[1][2]=0.5f*(g02+g12+g22);
  a[2][0]=0.5f*(g00-g10+g20); a[2][1]=0.5f*(g01-g11+g21); a[2][2]=0.5f*(g02-g12+g22);
  a[3][0]=g20; a[3][1]=g21; a[3][2]=g22;
  const int p_old = (co >> 5) * 16 + (co & 15);   // 0..63
  const int h = (co & 31) >> 4;
  const int gg = p_old >> 4, col = p_old & 15;
  const int P = (gg >> 1) * 32 + col * 2 + (gg & 1);
#pragma unroll
  for (int r4 = 0; r4 < 4; ++r4) {
    float u0 = a[r4][0];
    float u1 = 0.5f * (a[r4][0] + a[r4][1] + a[r4][2]);
    float u2 = 0.5f * (a[r4][0] - a[r4][1] + a[r4][2]);
    float u3 = a[r4][2];
    float uv[4] = {u0, u1, u2, u3};
#pragma unroll
    for (int c4 = 0; c4 < 4; ++c4) {
      int pos = r4 * 4 + c4;
      dst[(((size_t)pos * 256 + ci) * 64 + P) * 2 + h] = uv[c4];
    }
  }
}

// R24/R25: all weight transforms + conv1 wino input transform, one grid.
// Blocks [0,1879) = weights; [1879, 5975) = wino_in.
__global__ void wtrans_wino_in(
  const float* __restrict__ b1w, const float* __restrict__ c1w,
  const float* __restrict__ b2w, const float* __restrict__ c2w,
  const float* __restrict__ b3w, const float* __restrict__ b4w,
  const float* __restrict__ c3w, const float* __restrict__ features,
  float* __restrict__ ub, float* __restrict__ uc,
  float* __restrict__ u2b, float* __restrict__ u2c,
  float* __restrict__ wp3b, float* __restrict__ wt4b, float* __restrict__ wt3c,
  float* __restrict__ V)
{
  const int bx = blockIdx.x;
  if (bx < 1879) {
    int j = bx * 256 + threadIdx.x;
    if (j < 131072) { seg_wino_u(b1w, ub, j); return; } j -= 131072;
    if (j < 131072) { seg_wino_u(c1w, uc, j); return; } j -= 131072;
    if (j < 32768)  { seg_wino_u2(b2w, u2b, j); return; } j -= 32768;
    if (j < 32768)  { seg_wino_u2(c2w, u2c, j); return; } j -= 32768;
    if (j < 147456) { seg_pack_pk<128, 128>(b3w, wp3b, j); return; } j -= 147456;
    if (j < 4608)   { seg_tr<36, 128>(b4w, wt4b, j); return; }  j -= 4608;
    if (j < 1152)   { seg_tr<9, 128>(c3w, wt3c, j); return; }
    return;
  }
  // ---- wino_in: V = B^T d B per (b, ci, tile) ----
  const int idx = bx - 1879;            // 0..4095
  const int b = idx >> 7, cig = idx & 127;
  const int tid = threadIdx.x;
  if (tid >= 196) return;
  const int ci = cig * 4 + tid / 49;
  const int t  = tid % 49;
  const int ty = t / 7, tx = t % 7;
  const float* fp = features + ((size_t)b * 512 + ci) * 196;
  const int y0 = 2 * ty - 1, x0 = 2 * tx - 1;
  float d[4][4];
#pragma unroll
  for (int i = 0; i < 4; ++i) {
    const int y = y0 + i;
#pragma unroll
    for (int j = 0; j < 4; ++j) {
      const int x = x0 + j;
      d[i][j] = (y >= 0 && y < 14 && x >= 0 && x < 14) ? fp[y * 14 + x] : 0.0f;
    }
  }
  float tr[4][4];
#pragma unroll
  for (int j = 0; j < 4; ++j) {
    tr[0][j] = d[0][j] - d[2][j];
    tr[1][j] = d[1][j] + d[2][j];
    tr[2][j] = d[2][j] - d[1][j];
    tr[3][j] = d[1][j] - d[3][j];
  }
  const size_t m = (size_t)b * 49 + t;
#pragma unroll
  for (int i = 0; i < 4; ++i) {
    float v0 = tr[i][0] - tr[i][2];
    float v1 = tr[i][1] + tr[i][2];
    float v2 = tr[i][2] - tr[i][1];
    float v3 = tr[i][1] - tr[i][3];
    V[((size_t)(i * 4 + 0) * 512 + ci) * 1568 + m] = v0;
    V[((size_t)(i * 4 + 1) * 512 + ci) * 1568 + m] = v1;
    V[((size_t)(i * 4 + 2) * 512 + ci) * 1568 + m] = v2;
    V[((size_t)(i * 4 + 3) * 512 + ci) * 1568 + m] = v3;
  }
}

// ---------------- Winograd GEMM conv1 (R22 proven; 16-ci/(256,2) only spill-free pt) ----------------
__global__ __launch_bounds__(256, 2) void wino_gemm(
    const float* __restrict__ V, const float* __restrict__ U, float* __restrict__ M)
{
  const int pos = blockIdx.x;     // 0..15
  const int mb  = blockIdx.y;     // 0..24
  const int q   = blockIdx.z;     // 0..3
  const int head = q >> 1;
  const int pb   = q & 1;
  const int tid = threadIdx.x;
  const int col = tid & 15;
  const int r   = tid >> 4;
  const int wv  = tid >> 6;

  __shared__ float vbuf[2][16][64];
  __shared__ float ubuf[2][16][128];

  const float* Uh = U + (size_t)head * 2097152;
  float* Mh = M + (size_t)head * 6422528;
  const int m0 = mb * 64;

  const float* vg  = V + ((size_t)pos * 512 + (tid >> 4)) * 1568 + m0 + (tid & 15) * 4;
  const int c1 = 256 + tid;
  const float* ug0 = Uh + ((size_t)pos * 512 + (tid >> 5)) * 256 + pb * 128 + (tid & 31) * 4;
  const float* ug1 = Uh + ((size_t)pos * 512 + (c1 >> 5)) * 256 + pb * 128 + (c1 & 31) * 4;
  float* vls = ((float*)vbuf) + wv * 256;
  float* uls = ((float*)ubuf) + wv * 256;

  gl_lds16(vg, vls);
  gl_lds16(ug0, uls);
  gl_lds16(ug1, uls + 1024);
  __syncthreads();

  v2f acc[4][4];
#pragma unroll
  for (int g = 0; g < 4; ++g)
#pragma unroll
    for (int j = 0; j < 4; ++j) acc[g][j] = (v2f)(0.0f);

  int cur = 0;
  for (int cb = 0; cb < 32; ++cb) {
    if (cb + 1 < 32) {
      const int nb = cur ^ 1;
      gl_lds16(vg + (size_t)(cb + 1) * 16 * 1568, vls + nb * 1024);
      gl_lds16(ug0 + (size_t)(cb + 1) * 16 * 256, uls + nb * 2048);
      gl_lds16(ug1 + (size_t)(cb + 1) * 16 * 256, uls + nb * 2048 + 1024);
    }
#pragma unroll
    for (int ci = 0; ci < 16; ++ci) {
      const float4* uq0 = (const float4*)&ubuf[cur][ci][col * 4];
      const float4* uq1 = (const float4*)&ubuf[cur][ci][64 + col * 4];
      float4 a = uq0[0], bq = uq1[0];
      v2f u2[4] = { (v2f){a.x, a.y}, (v2f){a.z, a.w},
                    (v2f){bq.x, bq.y}, (v2f){bq.z, bq.w} };
      const float4* vp = (const float4*)&vbuf[cur][ci][r * 4];
      float4 v0 = vp[0];
      float vv[4] = {v0.x, v0.y, v0.z, v0.w};
#pragma unroll
      for (int j = 0; j < 4; ++j) {
        v2f s2 = (v2f){vv[j], vv[j]};
#pragma unroll
        for (int g = 0; g < 4; ++g)
          acc[g][j] = __builtin_elementwise_fma(u2[g], s2, acc[g][j]);
      }
    }
    __syncthreads();
    cur ^= 1;
  }

  const int mm = m0 + r * 4;
  if (mm < 1568) {
#pragma unroll
    for (int g = 0; g < 4; ++g) {
      const int p = pb * 64 + g * 16 + col;
      const int cox = (p >> 4) * 32 + (p & 15);
      float* ox = Mh + ((size_t)pos * 256 + cox) * 1568 + mm;
      float* oy = ox + (size_t)16 * 1568;
#pragma unroll
      for (int j = 0; j < 4; ++j) { ox[j] = acc[g][j].x; oy[j] = acc[g][j].y; }
    }
  }
}

// ---------------- R25: Winograd GEMM conv2 (same body, conv2 constants) ----------------
// K=256 -> 16 phases; N=128 per head (no pb). Grid (16, 25, 2) = 800 blocks.
__global__ __launch_bounds__(256, 2) void wino_gemm2(
    const float* __restrict__ V2, const float* __restrict__ U2, float* __restrict__ M2)
{
  const int pos = blockIdx.x;     // 0..15
  const int mb  = blockIdx.y;     // 0..24
  const int head = blockIdx.z;    // 0..1
  const int tid = threadIdx.x;
  const int col = tid & 15;
  const int r   = tid >> 4;
  const int wv  = tid >> 6;

  __shared__ float vbuf[2][16][64];
  __shared__ float ubuf[2][16][128];

  const float* Vh = V2 + (size_t)head * 6422528;   // 16*256*1568
  const float* Uh = U2 + (size_t)head * 524288;    // 16*256*128
  float* Mh = M2 + (size_t)head * 3211264;         // 16*128*1568
  const int m0 = mb * 64;

  const float* vg  = Vh + ((size_t)pos * 256 + (tid >> 4)) * 1568 + m0 + (tid & 15) * 4;
  const float* ug0 = Uh + ((size_t)pos * 256 + (tid >> 5)) * 128 + (tid & 31) * 4;
  const float* ug1 = Uh + ((size_t)pos * 256 + 8 + (tid >> 5)) * 128 + (tid & 31) * 4;
  float* vls = ((float*)vbuf) + wv * 256;
  float* uls = ((float*)ubuf) + wv * 256;

  gl_lds16(vg, vls);
  gl_lds16(ug0, uls);
  gl_lds16(ug1, uls + 1024);
  __syncthreads();

  v2f acc[4][4];
#pragma unroll
  for (int g = 0; g < 4; ++g)
#pragma unroll
    for (int j = 0; j < 4; ++j) acc[g][j] = (v2f)(0.0f);

  int cur = 0;
  for (int cb = 0; cb < 16; ++cb) {
    if (cb + 1 < 16) {
      const int nb = cur ^ 1;
      gl_lds16(vg + (size_t)(cb + 1) * 16 * 1568, vls + nb * 1024);
      gl_lds16(ug0 + (size_t)(cb + 1) * 16 * 128, uls + nb * 2048);
      gl_lds16(ug1 + (size_t)(cb + 1) * 16 * 128, uls + nb * 2048 + 1024);
    }
#pragma unroll
    for (int ci = 0; ci < 16; ++ci) {
      const float4* uq0 = (const float4*)&ubuf[cur][ci][col * 4];
      const float4* uq1 = (const float4*)&ubuf[cur][ci][64 + col * 4];
      float4 a = uq0[0], bq = uq1[0];
      v2f u2[4] = { (v2f){a.x, a.y}, (v2f){a.z, a.w},
                    (v2f){bq.x, bq.y}, (v2f){bq.z, bq.w} };
      const float4* vp = (const float4*)&vbuf[cur][ci][r * 4];
      float4 v0 = vp[0];
      float vv[4] = {v0.x, v0.y, v0.z, v0.w};
#pragma unroll
      for (int j = 0; j < 4; ++j) {
        v2f s2 = (v2f){vv[j], vv[j]};
#pragma unroll
        for (int g = 0; g < 4; ++g)
          acc[g][j] = __builtin_elementwise_fma(u2[g], s2, acc[g][j]);
      }
    }
    __syncthreads();
    cur ^= 1;
  }

  const int mm = m0 + r * 4;
  if (mm < 1568) {
#pragma unroll
    for (int g = 0; g < 4; ++g) {
      const int p = g * 16 + col;                 // 0..63
      const int cox = (p >> 4) * 32 + (p & 15);
      float* ox = Mh + ((size_t)pos * 128 + cox) * 1568 + mm;
      float* oy = ox + (size_t)16 * 1568;
#pragma unroll
      for (int j = 0; j < 4; ++j) { ox[j] = acc[g][j].x; oy[j] = acc[g][j].y; }
    }
  }
}

// ---------------- R25: conv1 out-transform + GN, fused with conv2 in-transform ----------------
// Y = A^T M A -> +bias -> GELU -> GN(8ch) -> ylds[16][196] -> B^T y B -> V2.
// t1 is never materialized. Same math/order as wino_out_gn + wino_in.
__global__ __launch_bounds__(256) void wino_outin(
    const float* __restrict__ M,
    const float* __restrict__ bsb, const float* __restrict__ bsc,
    const float* __restrict__ gwb, const float* __restrict__ gwc,
    const float* __restrict__ gbb, const float* __restrict__ gbc,
    float* __restrict__ V2)
{
  const int bx = blockIdx.x;           // head = bx>>4, cog = bx&15
  const int b  = blockIdx.y;
  const int head = bx >> 4, cog = bx & 15;
  const int tid = threadIdx.x;
  const float* Mh = M + (size_t)head * 6422528;
  const float* bs = head ? bsc : bsb;
  const float* gw = head ? gwc : gwb;
  const float* gb = head ? gbc : gbb;
  float* Vh = V2 + (size_t)head * 6422528;
  const int co0 = cog * 16;

  __shared__ float red[4][4];
  __shared__ float stats[4];
  __shared__ float ylds[16][196];

  const bool pa = tid < 196;
  const int csub = tid / 49;
  const int t    = tid % 49;
  const int ty = t / 7, tx = t % 7;
  const size_t mt = (size_t)b * 49 + t;

  float y4[4][4];
  float s = 0.f, q = 0.f;
  if (pa) {
#pragma unroll
    for (int cc = 0; cc < 4; ++cc) {
      const int co = co0 + csub * 4 + cc;
      const float* mp = Mh + (size_t)co * 1568 + mt;
      float m16[16];
#pragma unroll
      for (int pos = 0; pos < 16; ++pos)
        m16[pos] = mp[(size_t)pos * 401408];
      float Z0[4], Z1[4];
#pragma unroll
      for (int j = 0; j < 4; ++j) {
        Z0[j] = m16[0 * 4 + j] + m16[1 * 4 + j] + m16[2 * 4 + j];
        Z1[j] = m16[1 * 4 + j] - m16[2 * 4 + j] - m16[3 * 4 + j];
      }
      const float bias = bs[co];
      float yv[4];
      yv[0] = Z0[0] + Z0[1] + Z0[2];
      yv[1] = Z0[1] - Z0[2] - Z0[3];
      yv[2] = Z1[0] + Z1[1] + Z1[2];
      yv[3] = Z1[1] - Z1[2] - Z1[3];
#pragma unroll
      for (int k = 0; k < 4; ++k) {
        float x = yv[k] + bias;
        float g = 0.5f * x * (1.0f + erff(x * 0.70710678118654752440f));
        y4[cc][k] = g;
        s += g; q += g * g;
      }
    }
  }
  float s0 = (pa && csub < 2) ? s : 0.f, q0 = (pa && csub < 2) ? q : 0.f;
  float s1 = (pa && csub >= 2) ? s : 0.f, q1 = (pa && csub >= 2) ? q : 0.f;
#pragma unroll
  for (int off = 32; off > 0; off >>= 1) {
    s0 += __shfl_down(s0, off, 64); q0 += __shfl_down(q0, off, 64);
    s1 += __shfl_down(s1, off, 64); q1 += __shfl_down(q1, off, 64);
  }
  const int wave = tid >> 6, lane = tid & 63;
  if (lane == 0) { red[wave][0] = s0; red[wave][1] = q0; red[wave][2] = s1; red[wave][3] = q1; }
  __syncthreads();
  if (tid == 0) {
    float S0 = red[0][0] + red[1][0] + red[2][0] + red[3][0];
    float Q0 = red[0][1] + red[1][1] + red[2][1] + red[3][1];
    float S1 = red[0][2] + red[1][2] + red[2][2] + red[3][2];
    float Q1 = red[0][3] + red[1][3] + red[2][3] + red[3][3];
    float m0 = S0 * (1.0f / 1568.0f);
    float v0 = Q0 * (1.0f / 1568.0f) - m0 * m0;
    float m1 = S1 * (1.0f / 1568.0f);
    float v1 = Q1 * (1.0f / 1568.0f) - m1 * m1;
    stats[0] = m0; stats[1] = 1.0f / sqrtf(v0 + 1e-5f);
    stats[2] = m1; stats[3] = 1.0f / sqrtf(v1 + 1e-5f);
  }
  __syncthreads();
  if (pa) {
    const float mg = (csub < 2) ? stats[0] : stats[2];
    const float iv = (csub < 2) ? stats[1] : stats[3];
#pragma unroll
    for (int cc = 0; cc < 4; ++cc) {
      const int co = co0 + csub * 4 + cc;
      const float w = gw[co], bb2 = gb[co];
#pragma unroll
      for (int dy = 0; dy < 2; ++dy)
#pragma unroll
        for (int dx = 0; dx < 2; ++dx) {
          float yv = (y4[cc][dy * 2 + dx] - mg) * iv * w + bb2;
          ylds[csub * 4 + cc][(2 * ty + dy) * 14 + (2 * tx + dx)] = yv;
        }
    }
  }
  __syncthreads();
  // ---- conv2 input transform: V2 = B^T y B for this block's 16 channels ----
  if (pa) {
    const int y0 = 2 * ty - 1, x0 = 2 * tx - 1;
#pragma unroll
    for (int cc = 0; cc < 4; ++cc) {
      const int cl = csub * 4 + cc;
      const int ci2 = co0 + cl;          // conv2 input channel 0..255
      float d[4][4];
#pragma unroll
      for (int i = 0; i < 4; ++i) {
        const int y = y0 + i;
#pragma unroll
        for (int j = 0; j < 4; ++j) {
          const int x = x0 + j;
          d[i][j] = (y >= 0 && y < 14 && x >= 0 && x < 14) ? ylds[cl][y * 14 + x] : 0.0f;
        }
      }
      float tr[4][4];
#pragma unroll
      for (int j = 0; j < 4; ++j) {
        tr[0][j] = d[0][j] - d[2][j];
        tr[1][j] = d[1][j] + d[2][j];
        tr[2][j] = d[2][j] - d[1][j];
        tr[3][j] = d[1][j] - d[3][j];
      }
#pragma unroll
      for (int i = 0; i < 4; ++i) {
        float v0 = tr[i][0] - tr[i][2];
        float v1 = tr[i][1] + tr[i][2];
        float v2 = tr[i][2] - tr[i][1];
        float v3 = tr[i][1] - tr[i][3];
        Vh[((size_t)(i * 4 + 0) * 256 + ci2) * 1568 + mt] = v0;
        Vh[((size_t)(i * 4 + 1) * 256 + ci2) * 1568 + mt] = v1;
        Vh[((size_t)(i * 4 + 2) * 256 + ci2) * 1568 + mt] = v2;
        Vh[((size_t)(i * 4 + 3) * 256 + ci2) * 1568 + mt] = v3;
      }
    }
  }
}

// ---------------- R25: conv2 out-transform + bias + GELU + GN -> t2b/t2c ----------------
__global__ __launch_bounds__(256) void wino_out_gn2(
    const float* __restrict__ M2,
    const float* __restrict__ bsb, const float* __restrict__ bsc,
    const float* __restrict__ gwb, const float* __restrict__ gwc,
    const float* __restrict__ gbb, const float* __restrict__ gbc,
    float* __restrict__ outb, float* __restrict__ outc)
{
  const int bx = blockIdx.x;           // 0..15: head = bx>>3, cog = bx&7
  const int b  = blockIdx.y;
  const int head = bx >> 3, cog = bx & 7;
  const int tid = threadIdx.x;
  const float* Mh = M2 + (size_t)head * 3211264;
  const float* bs = head ? bsc : bsb;
  const float* gw = head ? gwc : gwb;
  const float* gb = head ? gbc : gbb;
  float* out      = head ? outc : outb;
  const int co0 = cog * 16;

  __shared__ float red[4][4];
  __shared__ float stats[4];

  const bool pa = tid < 196;
  const int csub = tid / 49;
  const int t    = tid % 49;
  const int ty = t / 7, tx = t % 7;
  const size_t mt = (size_t)b * 49 + t;

  float y4[4][4];
  float s = 0.f, q = 0.f;
  if (pa) {
#pragma unroll
    for (int cc = 0; cc < 4; ++cc) {
      const int co = co0 + csub * 4 + cc;
      const float* mp = Mh + (size_t)co * 1568 + mt;
      float m16[16];
#pragma unroll
      for (int pos = 0; pos < 16; ++pos)
        m16[pos] = mp[(size_t)pos * 200704];   // pos stride = 128*1568
      float Z0[4], Z1[4];
#pragma unroll
      for (int j = 0; j < 4; ++j) {
        Z0[j] = m16[0 * 4 + j] + m16[1 * 4 + j] + m16[2 * 4 + j];
        Z1[j] = m16[1 * 4 + j] - m16[2 * 4 + j] - m16[3 * 4 + j];
      }
      const float bias = bs[co];
      float yv[4];
      yv[0] = Z0[0] + Z0[1] + Z0[2];
      yv[1] = Z0[1] - Z0[2] - Z0[3];
      yv[2] = Z1[0] + Z1[1] + Z1[2];
      yv[3] = Z1[1] - Z1[2] - Z1[3];
#pragma unroll
      for (int k = 0; k < 4; ++k) {
        float x = yv[k] + bias;
        float g = 0.5f * x * (1.0f + erff(x * 0.70710678118654752440f));
        y4[cc][k] = g;
        s += g; q += g * g;
      }
    }
  }
  float s0 = (pa && csub < 2) ? s : 0.f, q0 = (pa && csub < 2) ? q : 0.f;
  float s1 = (pa && csub >= 2) ? s : 0.f, q1 = (pa && csub >= 2) ? q : 0.f;
#pragma unroll
  for (int off = 32; off > 0; off >>= 1) {
    s0 += __shfl_down(s0, off, 64); q0 += __shfl_down(q0, off, 64);
    s1 += __shfl_down(s1, off, 64); q1 += __shfl_down(q1, off, 64);
  }
  const int wave = tid >> 6, lane = tid & 63;
  if (lane == 0) { red[wave][0] = s0; red[wave][1] = q0; red[wave][2] = s1; red[wave][3] = q1; }
  __syncthreads();
  if (tid == 0) {
    float S0 = red[0][0] + red[1][0] + red[2][0] + red[3][0];
    float Q0 = red[0][1] + red[1][1] + red[2][1] + red[3][1];
    float S1 = red[0][2] + red[1][2] + red[2][2] + red[3][2];
    float Q1 = red[0][3] + red[1][3] + red[2][3] + red[3][3];
    float m0 = S0 * (1.0f / 1568.0f);
    float v0 = Q0 * (1.0f / 1568.0f) - m0 * m0;
    float m1 = S1 * (1.0f / 1568.0f);
    float v1 = Q1 * (1.0f / 1568.0f) - m1 * m1;
    stats[0] = m0; stats[1] = 1.0f / sqrtf(v0 + 1e-5f);
    stats[2] = m1; stats[3] = 1.0f / sqrtf(v1 + 1e-5f);
  }
  __syncthreads();
  if (pa) {
    const float mg = (csub < 2) ? stats[0] : stats[2];
    const float iv = (csub < 2) ? stats[1] : stats[3];
#pragma unroll
    for (int cc = 0; cc < 4; ++cc) {
      const int co = co0 + csub * 4 + cc;
      const float w = gw[co], bb2 = gb[co];
      float* op = out + ((size_t)b * 128 + co) * 196;
#pragma unroll
      for (int dy = 0; dy < 2; ++dy)
#pragma unroll
        for (int dx = 0; dx < 2; ++dx) {
          float yv = (y4[cc][dy * 2 + dx] - mg) * iv * w + bb2;
          op[(2 * ty + dy) * 14 + (2 * tx + dx)] = yv;
        }
    }
  }
}

// ---------------- split-K partial conv3x3 (conv3 direct path) ----------------
// NOTE (R10): MFMA/bf16 conv precision-blocked; keep fp32.
// NOTE (R11-R16): ILP/occupancy/setprio null; LDS-staged weights + 1-barrier dbuf load-bearing.
template<int COPT>
__global__ __launch_bounds__(256, 2) void conv3x3_part(
    const float* __restrict__ in0, const float* __restrict__ in1,
    const float* __restrict__ wt0, const float* __restrict__ wt1,
    float* __restrict__ po0, float* __restrict__ po1,
    int Cin, int Cout, int cobPerHead, int cinPerSplit, size_t sStride)
{
  constexpr int NP = COPT / 2;
  constexpr int NPP = 16 * NP;
  constexpr int NPAIR = 8 * NPP;
  const int tid = threadIdx.x;
  const int bx  = blockIdx.x;
  const int b   = blockIdx.y;
  const int s   = blockIdx.z;
  const int head = bx / cobPerHead;
  const int cob  = bx - head * cobPerHead;
  const float* in  = head ? in1  : in0;
  const float* wt  = head ? wt1  : wt0;
  float* po        = head ? po1  : po0;
  const int co0 = cob * (16 * COPT);

  const int col = tid & 15;
  const int r   = tid >> 4;
  const bool ract = r < 14;

  __shared__ float tile[2][CHUNK][16][16];
  __shared__ float wbuf[2][8][NPP][20];

  {
    float* tz = &tile[0][0][0][0];
    for (int i = tid; i < 2 * CHUNK * 256; i += 256) tz[i] = 0.0f;
  }
  __syncthreads();

  const int p = tid;
  const bool pa = p < 196;
  const int prow = p / 14, pcol = p - prow * 14;
  const float* inb = in + (size_t)b * Cin * 196;
  const int cb0 = (s * cinPerSplit) / CHUNK;
  const int nch = cinPerSplit / CHUNK;
  const int CoutH = Cout >> 1;

  const int sciL = tid / NPP;
  const int spp  = tid - sciL * NPP;
  const bool sact = tid < NPAIR;
  const int spidx = ((co0 >> 5) + (spp >> 4)) * 16 + (spp & 15);

  if (pa) {
#pragma unroll
    for (int ci = 0; ci < CHUNK; ++ci)
      tile[0][ci][prow + 1][pcol + 1] = inb[(cb0 * CHUNK + ci) * 196 + p];
  }
  if (sact) {
    const float4* src = (const float4*)(wt + ((size_t)(cb0 * CHUNK + sciL) * CoutH + spidx) * 20);
    float4 q0 = src[0], q1 = src[1], q2 = src[2], q3 = src[3], q4 = src[4];
    float4* dst = (float4*)&wbuf[0][sciL][spp][0];
    dst[0] = q0; dst[1] = q1; dst[2] = q2; dst[3] = q3; dst[4] = q4;
  }
  __syncthreads();

  v2f acc[NP][14];
#pragma unroll
  for (int g = 0; g < NP; ++g)
#pragma unroll
    for (int j = 0; j < 14; ++j) acc[g][j] = (v2f)(0.0f);

  int wcur = 0;
  for (int lcb = 0; lcb < nch; ++lcb) {
    const int cbg = cb0 + lcb;
    const int cur = lcb & 1;
    const bool more = (lcb + 1 < nch);
    float v[CHUNK];
    if (more && pa) {
#pragma unroll
      for (int ci = 0; ci < CHUNK; ++ci)
        v[ci] = inb[((cbg + 1) * CHUNK + ci) * 196 + p];
    }
#pragma unroll
    for (int half = 0; half < 2; ++half) {
      const bool hasNext = (half == 0) || more;
      const int nbase = (half == 0) ? (cbg * CHUNK + 8) : ((cbg + 1) * CHUNK);
      float4 q0, q1, q2, q3, q4;
      if (hasNext && sact) {
        const float4* src = (const float4*)(wt + ((size_t)(nbase + sciL) * CoutH + spidx) * 20);
        q0 = src[0]; q1 = src[1]; q2 = src[2]; q3 = src[3]; q4 = src[4];
      }
      if (ract) {
#pragma unroll
        for (int ciL = 0; ciL < 8; ++ciL) {
          const int ci = half * 8 + ciL;
          v2f w2[NP][9];
#pragma unroll
          for (int g = 0; g < NP; ++g) {
            const float4* wq = (const float4*)&wbuf[wcur][ciL][g * 16 + col][0];
            float4 a0 = wq[0], a1 = wq[1], a2 = wq[2], a3 = wq[3], a4 = wq[4];
            w2[g][0] = (v2f){a0.x, a0.y}; w2[g][1] = (v2f){a0.z, a0.w};
            w2[g][2] = (v2f){a1.x, a1.y}; w2[g][3] = (v2f){a1.z, a1.w};
            w2[g][4] = (v2f){a2.x, a2.y}; w2[g][5] = (v2f){a2.z, a2.w};
            w2[g][6] = (v2f){a3.x, a3.y}; w2[g][7] = (v2f){a3.z, a3.w};
            w2[g][8] = (v2f){a4.x, a4.y};
          }
          float nb[3][16];
#pragma unroll
          for (int dr = 0; dr < 3; ++dr) {
            const float4* rp = (const float4*)(&tile[cur][ci][r + dr][0]);
            float4 a = rp[0], bq = rp[1], cq = rp[2], dq = rp[3];
            nb[dr][0]  = a.x;  nb[dr][1]  = a.y;  nb[dr][2]  = a.z;  nb[dr][3]  = a.w;
            nb[dr][4]  = bq.x; nb[dr][5]  = bq.y; nb[dr][6]  = bq.z; nb[dr][7]  = bq.w;
            nb[dr][8]  = cq.x; nb[dr][9]  = cq.y; nb[dr][10] = cq.z; nb[dr][11] = cq.w;
            nb[dr][12] = dq.x; nb[dr][13] = dq.y; nb[dr][14] = dq.z; nb[dr][15] = dq.w;
          }
#pragma unroll
          for (int ky = 0; ky < 3; ++ky)
#pragma unroll
            for (int kx = 0; kx < 3; ++kx) {
#pragma unroll
              for (int g = 0; g < NP; ++g) {
                v2f w = w2[g][ky * 3 + kx];
#pragma unroll
                for (int j = 0; j < 14; ++j) {
                  float s_ = nb[ky][j + kx];
                  v2f nbv = (v2f){s_, s_};
                  acc[g][j] = __builtin_elementwise_fma(w, nbv, acc[g][j]);
                }
              }
            }
        }
      }
      if (hasNext && sact) {
        float4* dst = (float4*)&wbuf[wcur ^ 1][sciL][spp][0];
        dst[0] = q0; dst[1] = q1; dst[2] = q2; dst[3] = q3; dst[4] = q4;
      }
      if (half == 1 && more && pa) {
#pragma unroll
        for (int ci = 0; ci < CHUNK; ++ci)
          tile[1 - cur][ci][prow + 1][pcol + 1] = v[ci];
      }
      __syncthreads();
      wcur ^= 1;
    }
  }

  if (ract) {
#pragma unroll
    for (int g = 0; g < NP; ++g) {
      const int ocx = 32 * g + col;
      const int ocy = ocx + 16;
      float* opx = po + (size_t)s * sStride + ((size_t)b * Cout + co0 + ocx) * 196 + r * 14;
      float* opy = po + (size_t)s * sStride + ((size_t)b * Cout + co0 + ocy) * 196 + r * 14;
#pragma unroll
      for (int j = 0; j < 14; ++j) { opx[j] = acc[g][j].x; opy[j] = acc[g][j].y; }
    }
  }
}

// ---------------- combine partials + bias + GELU + GroupNorm (conv3) ----------------
template<int S>
__global__ __launch_bounds__(256) void combine_gn(
    const float* __restrict__ po0, const float* __restrict__ po1,
    const float* __restrict__ bs0, const float* __restrict__ bs1,
    const float* __restrict__ gw0, const float* __restrict__ gw1,
    const float* __restrict__ gb0, const float* __restrict__ gb1,
    float* __restrict__ out0, float* __restrict__ out1,
    int Cout, int cobPerHead, size_t sStride)
{
  const int tid = threadIdx.x, bx = blockIdx.x, b = blockIdx.y;
  const int head = bx / cobPerHead, cob = bx - head * cobPerHead;
  const float* po = head ? po1 : po0;
  const float* bs = head ? bs1 : bs0;
  const float* gw = head ? gw1 : gw0;
  const float* gb = head ? gb1 : gb0;
  float* out      = head ? out1 : out0;
  const int co0 = cob * 16;

  __shared__ float red[4][4];
  __shared__ float stats[4];

  const int p = tid;
  const bool pa = p < 196;
  float v[16];
  float s0 = 0.f, q0 = 0.f, s1 = 0.f, q1 = 0.f;
  if (pa) {
#pragma unroll
    for (int c = 0; c < 16; ++c) {
      const size_t base = ((size_t)b * Cout + co0 + c) * 196 + p;
      float x = bs[co0 + c];
#pragma unroll
      for (int s = 0; s < S; ++s) x += po[base + (size_t)s * sStride];
      float g = 0.5f * x * (1.0f + erff(x * 0.70710678118654752440f));
      v[c] = g;
      if (c < 8) { s0 += g; q0 += g * g; } else { s1 += g; q1 += g * g; }
    }
  }
#pragma unroll
  for (int off = 32; off > 0; off >>= 1) {
    s0 += __shfl_down(s0, off, 64); q0 += __shfl_down(q0, off, 64);
    s1 += __shfl_down(s1, off, 64); q1 += __shfl_down(q1, off, 64);
  }
  const int wave = tid >> 6, lane = tid & 63;
  if (lane == 0) { red[wave][0] = s0; red[wave][1] = q0; red[wave][2] = s1; red[wave][3] = q1; }
  __syncthreads();
  if (tid == 0) {
    float S0 = red[0][0] + red[1][0] + red[2][0] + red[3][0];
    float Q0 = red[0][1] + red[1][1] + red[2][1] + red[3][1];
    float S1 = red[0][2] + red[1][2] + red[2][2] + red[3][2];
    float Q1 = red[0][3] + red[1][3] + red[2][3] + red[3][3];
    float m0 = S0 * (1.0f / 1568.0f);
    float v0 = Q0 * (1.0f / 1568.0f) - m0 * m0;
    float m1 = S1 * (1.0f / 1568.0f);
    float v1 = Q1 * (1.0f / 1568.0f) - m1 * m1;
    stats[0] = m0; stats[1] = 1.0f / sqrtf(v0 + 1e-5f);
    stats[2] = m1; stats[3] = 1.0f / sqrtf(v1 + 1e-5f);
  }
  __syncthreads();
  if (pa) {
    float m0 = stats[0], i0 = stats[1], m1 = stats[2], i1 = stats[3];
#pragma unroll
    for (int c = 0; c < 16; ++c) {
      float m  = (c < 8) ? m0 : m1;
      float iv = (c < 8) ? i0 : i1;
      float y = (v[c] - m) * iv * gw[co0 + c] + gb[co0 + c];
      out[((size_t)b * Cout + co0 + c) * 196 + p] = y;
    }
  }
}

// ---------------- fused 1x1 heads + per-image greedy NMS (R16) ----------------
__global__ __launch_bounds__(512) void nms_kernel(
  const float* __restrict__ tb, const float* __restrict__ tc,
  const float* __restrict__ wtb, const float* __restrict__ wtc,
  const float* __restrict__ bb,  const float* __restrict__ bc,
  float* __restrict__ bbox, float* __restrict__ out)
{
  const int b = blockIdx.x, tid = threadIdx.x;
  __shared__ unsigned long long key[SORTN];
  __shared__ float sx1[NN], sy1[NN], sx2[NN], sy2[NN], sar[NN], ssc[NN];
  __shared__ unsigned char sup[NN];
  __shared__ int sV, sMin;

  if (tid == 0) sV = 0;
  for (int i = NN + tid; i < SORTN; i += 512) key[i] = 0ull;

  int cntv = 0;
  if (tid < 196) {
    const int p = tid;
    float ab[36], ac[9];
#pragma unroll
    for (int o = 0; o < 36; ++o) ab[o] = bb[o];
#pragma unroll
    for (int o = 0; o < 9; ++o)  ac[o] = bc[o];
    const float* pb = tb + (size_t)b * 128 * 196 + p;
    const float* pc = tc + (size_t)b * 128 * 196 + p;
    for (int ci = 0; ci < 128; ++ci) {
      float xb = pb[ci * 196];
      float xc = pc[ci * 196];
      const float* wB = wtb + ci * 36;
      const float* wC = wtc + ci * 9;
#pragma unroll
      for (int o = 0; o < 36; ++o) ab[o] = fmaf(wB[o], xb, ab[o]);
#pragma unroll
      for (int o = 0; o < 9; ++o)  ac[o] = fmaf(wC[o], xc, ac[o]);
    }
    float* bp = bbox + ((size_t)b * NN) * 4 + (size_t)p * 36;
#pragma unroll
    for (int o = 0; o < 36; ++o) bp[o] = ab[o];
#pragma unroll
    for (int a = 0; a < 9; ++a) {
      float s = 1.0f / (1.0f + expf(-ac[a]));
      const int n = p * 9 + a;
      unsigned rank = (unsigned)(NN - 1 - n);
      unsigned long long k;
      if (s > 0.5f) { k = (((unsigned long long)__float_as_uint(s)) << 32) | rank; cntv++; }
      else k = (unsigned long long)rank;
      key[n] = k;
    }
  }
  atomicAdd(&sV, cntv);
  __syncthreads();
  const int V = sV;

  for (int kk = 2; kk <= SORTN; kk <<= 1) {
    for (int j = kk >> 1; j > 0; j >>= 1) {
      for (int i = tid; i < SORTN; i += 512) {
        int ixj = i ^ j;
        if (ixj > i) {
          unsigned long long a = key[i], c = key[ixj];
          bool dirDesc = ((i & kk) == 0);
          if ((a < c) == dirDesc) { key[i] = c; key[ixj] = a; }
        }
      }
      __syncthreads();
    }
  }

  const float* bbb = bbox + (size_t)b * NN * 4;
  for (int i = tid; i < V; i += 512) {
    unsigned long long k = key[i];
    int idx = NN - 1 - (int)(unsigned)(k & 0xFFFFFFFFull);
    float s = __uint_as_float((unsigned)(k >> 32));
    const float* bp = bbb + (size_t)idx * 4;
    float x1 = fminf(fmaxf(bp[0], 0.0f), 1.0f);
    float y1 = fminf(fmaxf(bp[1], 0.0f), 1.0f);
    float x2 = fminf(fmaxf(bp[2], 0.0f), 1.0f);
    float y2 = fminf(fmaxf(bp[3], 0.0f), 1.0f);
    sx1[i] = x1; sy1[i] = y1; sx2[i] = x2; sy2[i] = y2;
    sar[i] = (x2 - x1) * (y2 - y1);
    ssc[i] = s;
    sup[i] = 0;
  }
  __syncthreads();

  int kept = 0, cur = 0;
  float* ob = out + (size_t)b * 50 * 5;
  while (kept < 50 && cur < V) {
    int nxt = -1;
    for (int base = cur; base < V; base += 512) {
      if (tid == 0) sMin = 0x7FFFFFFF;
      __syncthreads();
      int i = base + tid;
      if (i < V && !sup[i]) atomicMin(&sMin, i);
      __syncthreads();
      if (sMin != 0x7FFFFFFF) { nxt = sMin; break; }
    }
    if (nxt < 0) break;
    float kx1 = sx1[nxt], ky1 = sy1[nxt], kx2 = sx2[nxt], ky2 = sy2[nxt], ka = sar[nxt];
    if (tid == 0) {
      float* rr = ob + kept * 5;
      rr[0] = kx1; rr[1] = ky1; rr[2] = kx2; rr[3] = ky2; rr[4] = ssc[nxt];
    }
    kept++;
    for (int jj = nxt + 1 + tid; jj < V; jj += 512) {
      if (!sup[jj]) {
        float xx1 = fmaxf(kx1, sx1[jj]);
        float yy1 = fmaxf(ky1, sy1[jj]);
        float xx2 = fminf(kx2, sx2[jj]);
        float yy2 = fminf(ky2, sy2[jj]);
        float inter = fmaxf(xx2 - xx1, 0.0f) * fmaxf(yy2 - yy1, 0.0f);
        float iou = inter / ((ka + sar[jj]) - inter);
        if (!(iou < 0.3f)) sup[jj] = 1;
      }
    }
    cur = nxt + 1;
    __syncthreads();
  }
  for (int rr = kept + tid; rr < 50; rr += 512) {
    float* qq = ob + rr * 5;
    qq[0] = 0.0f; qq[1] = 0.0f; qq[2] = 0.0f; qq[3] = 0.0f; qq[4] = -1.0f;
  }
}

// ---------------- launch ----------------
extern "C" void kernel_launch(void* const* d_in, const int* in_sizes, int n_in,
                              void* d_out, int out_size, void* d_ws, size_t ws_size,
                              hipStream_t stream)
{
  const float* features = (const float*)d_in[0];
  const float* b1w = (const float*)d_in[1];  const float* b1b = (const float*)d_in[2];
  const float* bg1w = (const float*)d_in[3]; const float* bg1b = (const float*)d_in[4];
  const float* b2w = (const float*)d_in[5];  const float* b2b = (const float*)d_in[6];
  const float* bg2w = (const float*)d_in[7]; const float* bg2b = (const float*)d_in[8];
  const float* b3w = (const float*)d_in[9];  const float* b3b = (const float*)d_in[10];
  const float* bg3w = (const float*)d_in[11]; const float* bg3b = (const float*)d_in[12];
  const float* b4w = (const float*)d_in[13]; const float* b4b = (const float*)d_in[14];
  const float* c1w = (const float*)d_in[15]; const float* c1b = (const float*)d_in[16];
  const float* cg1w = (const float*)d_in[17]; const float* cg1b = (const float*)d_in[18];
  const float* c2w = (const float*)d_in[19]; const float* c2b = (const float*)d_in[20];
  const float* cg2w = (const float*)d_in[21]; const float* cg2b = (const float*)d_in[22];
  const float* c3w = (const float*)d_in[23]; const float* c3b = (const float*)d_in[24];

  float* ws = (float*)d_ws;
  float* U    = ws; ws += 4194304;   // conv1 wino U: 2 x 16 x 512 x 256
  float* U2   = ws; ws += 1048576;   // conv2 wino U: 2 x 16 x 256 x 128
  float* wp3b = ws; ws += 163840;
  float* wt4b = ws; ws += 4608;
  float* wt3c = ws; ws += 1152;
  float* t2b  = ws; ws += 802816;    // 32*128*196
  float* t2c  = ws; ws += 802816;
  float* t3   = ws; ws += 802816;
  float* V    = ws; ws += 12845056;  // conv1 V (16x512x1568) -> reused as conv2 V2 (2x16x256x1568)
  float* M    = ws; ws += 12845056;  // conv1 M (2x16x256x1568) -> reused as conv2 M2 (2x16x128x1568)
  float* bbox = ws; ws += 225792;
  float* P    = V;                   // conv3 partials alias V (V2 dead after gemm2)

  // 1. all weight transforms + conv1 input transform
  wtrans_wino_in<<<5975, 256, 0, stream>>>(b1w, c1w, b2w, c2w, b3w, b4w, c3w,
                                           features,
                                           U, U + 2097152, U2, U2 + 524288,
                                           wp3b, wt4b, wt3c, V);
  // 2. conv1 GEMM
  wino_gemm<<<dim3(16, 25, 4), 256, 0, stream>>>(V, U, M);
  // 3. conv1 out-transform + GN fused with conv2 in-transform (t1 never materialized)
  wino_outin<<<dim3(32, 32), 256, 0, stream>>>(M, b1b, c1b, bg1w, cg1w, bg1b, cg1b, V);
  // 4. conv2 GEMM
  wino_gemm2<<<dim3(16, 25, 2), 256, 0, stream>>>(V, U2, M);
  // 5. conv2 out-transform + GN
  wino_out_gn2<<<dim3(16, 32), 256, 0, stream>>>(M, b2b, c2b, bg2w, cg2w, bg2b, cg2b, t2b, t2c);

  // conv3 (bbox only): direct path, Cin=128, Cout=128, COPT=2, S=4
  {
    const size_t sStr = (size_t)32 * 128 * 196;
    conv3x3_part<2><<<dim3(4, 32, 4), 256, 0, stream>>>(
        t2b, t2b, wp3b, wp3b, P, P, 128, 128, 4, 32, sStr);
    combine_gn<4><<<dim3(8, 32), 256, 0, stream>>>(
        P, P, b3b, b3b, bg3w, bg3w, bg3b, bg3b, t3, t3, 128, 8, sStr);
  }

  nms_kernel<<<32, 512, 0, stream>>>(t3, t2c, wt4b, wt3c, b4b, c3b, bbox, (float*)d_out);
}